// Round 6
// baseline (164.358 us; speedup 1.0000x reference)
//
#include <hip/hip_runtime.h>

// ---------------------------------------------------------------------------
// Fused pre-LN MHA block on MI355X (gfx950).
// B=2, L=2048, D=768, H=12, Dh=64.  All matmuls via mfma_f32_16x16x32_bf16.
// Pipeline: LN -> (cvt weights) -> GEMM1 (qkv) -> flash-attn -> GEMM2+residual
// R5: attn — 2 waves x 32 q-rows (halves K/V LDS read duplication on the DS
// pipe), permlane32_swap for xor-32 reduces (VALU pipe), mq-extended P swizzle.
// ---------------------------------------------------------------------------

#define DEV __device__ __forceinline__

typedef __attribute__((ext_vector_type(4))) float f32x4;
typedef __attribute__((ext_vector_type(8))) short s16x8;
typedef __attribute__((ext_vector_type(2))) int i32x2;

constexpr int Bb   = 2;
constexpr int Ll   = 2048;
constexpr int Dd   = 768;
constexpr int Hh   = 12;
constexpr int Dh   = 64;
constexpr int Mrows = Bb * Ll;      // 4096
constexpr int N1   = 3 * Dd;        // 2304

DEV unsigned short f2bf(float f) {
  union { float f; unsigned u; } v; v.f = f;
  unsigned r = v.u + 0x7fffu + ((v.u >> 16) & 1u);
  return (unsigned short)(r >> 16);
}

DEV void gload_lds16(const void* g, void* l) {
  __builtin_amdgcn_global_load_lds((const __attribute__((address_space(1))) unsigned int*)g,
                                   (__attribute__((address_space(3))) unsigned int*)l,
                                   16, 0, 0);
}

DEV f32x4 mfma16(s16x8 a, s16x8 b, f32x4 c) {
  return __builtin_amdgcn_mfma_f32_16x16x32_bf16(a, b, c, 0, 0, 0);
}

// full-wave reduce: in-lane value -> max/sum over lanes {l, l^16, l^32, l^48}
// xor-16 via ds_swizzle (shfl), xor-32 via v_permlane32_swap_b32 (VALU pipe).
DEV float redmax64(float x) {
  x = fmaxf(x, __shfl_xor(x, 16, 64));
  float a = x, b = x;
  asm volatile("v_permlane32_swap_b32 %0, %1" : "+v"(a), "+v"(b));
  return fmaxf(a, b);
}
DEV float redsum64(float x) {
  x += __shfl_xor(x, 16, 64);
  float a = x, b = x;
  asm volatile("v_permlane32_swap_b32 %0, %1" : "+v"(a), "+v"(b));
  return a + b;
}

// ---------------------------------------------------------------------------
// Kernel 1: LayerNorm fp32 -> bf16.  One block per row (768 elems, 256 thr).
// ---------------------------------------------------------------------------
__global__ __launch_bounds__(256) void ln_kernel(const float* __restrict__ x,
                                                 const float* __restrict__ gamma,
                                                 const float* __restrict__ beta,
                                                 short* __restrict__ hbuf) {
  const int row = blockIdx.x, t = threadIdx.x;
  const float* xr = x + (size_t)row * Dd;
  float v0 = xr[t], v1 = xr[t + 256], v2 = xr[t + 512];
  float s = v0 + v1 + v2;
  float q = v0 * v0 + v1 * v1 + v2 * v2;
#pragma unroll
  for (int off = 32; off; off >>= 1) {
    s += __shfl_xor(s, off, 64);
    q += __shfl_xor(q, off, 64);
  }
  __shared__ float red[8];
  const int w = t >> 6, lane = t & 63;
  if (lane == 0) { red[w] = s; red[4 + w] = q; }
  __syncthreads();
  s = red[0] + red[1] + red[2] + red[3];
  q = red[4] + red[5] + red[6] + red[7];
  const float mean = s * (1.f / Dd);
  const float var  = q * (1.f / Dd) - mean * mean;
  const float rstd = rsqrtf(var + 1e-5f);
  short* hr = hbuf + (size_t)row * Dd;
  hr[t]       = (short)f2bf((v0 - mean) * rstd * gamma[t]       + beta[t]);
  hr[t + 256] = (short)f2bf((v1 - mean) * rstd * gamma[t + 256] + beta[t + 256]);
  hr[t + 512] = (short)f2bf((v2 - mean) * rstd * gamma[t + 512] + beta[t + 512]);
}

// ---------------------------------------------------------------------------
// Kernel 2: convert w1 [2304*768] and w2 [768*768] fp32 -> bf16.
// ---------------------------------------------------------------------------
constexpr int W1E = N1 * Dd;     // 1769472
constexpr int W2E = Dd * Dd;     // 589824
__global__ __launch_bounds__(256) void cvt_kernel(const float* __restrict__ w1,
                                                  const float* __restrict__ w2,
                                                  short* __restrict__ w1b,
                                                  short* __restrict__ w2b) {
  int i = blockIdx.x * 256 + threadIdx.x;
  const int stride = gridDim.x * 256;
  for (; i < W1E + W2E; i += stride) {
    if (i < W1E) w1b[i] = (short)f2bf(w1[i]);
    else         w2b[i - W1E] = (short)f2bf(w2[i - W1E]);
  }
}

// ---------------------------------------------------------------------------
// GEMM (B^T form): C[m][n] = sum_k A[m][k] * W[n][k] (+bias)(+resid)
// 128x128 tile, BK=64, 4 waves (2x2), each wave 64x64 = 4x4 16x16 frags.
// LDS tiles XOR-swizzled via pre-swizzled global source (m173 pattern).
// ---------------------------------------------------------------------------
template <int EPI, int WSRC>
__global__ __launch_bounds__(256) void gemm_bt(const short* __restrict__ A,
                                               const void* __restrict__ Wp,
                                               const float* __restrict__ bias,
                                               const float* __restrict__ resid,
                                               void* __restrict__ outp,
                                               int N, int K) {
  __shared__ __align__(16) short As[128 * 64];
  __shared__ __align__(16) short Ws[128 * 64];
  const int tid  = threadIdx.x;
  const int lane = tid & 63, wid = tid >> 6;
  const int wr = wid >> 1, wc = wid & 1;
  const int g = lane >> 4, li = lane & 15;
  const int brow = blockIdx.y * 128, bcol = blockIdx.x * 128;

  f32x4 acc[4][4];
#pragma unroll
  for (int m = 0; m < 4; ++m)
#pragma unroll
    for (int n = 0; n < 4; ++n)
#pragma unroll
      for (int r = 0; r < 4; ++r) acc[m][n][r] = 0.f;

  for (int kt = 0; kt < K; kt += 64) {
#pragma unroll
    for (int i = 0; i < 4; ++i) {
      const int idx = i * 256 + tid;
      const int r = idx >> 3, c = idx & 7;
      const int cs = c ^ (r & 7);              // pre-swizzled source block
      gload_lds16(A + (size_t)(brow + r) * K + kt + cs * 8, (char*)As + idx * 16);
    }
    if constexpr (WSRC == 0) {
      const short* W = (const short*)Wp;
#pragma unroll
      for (int i = 0; i < 4; ++i) {
        const int idx = i * 256 + tid;
        const int r = idx >> 3, c = idx & 7;
        const int cs = c ^ (r & 7);
        gload_lds16(W + (size_t)(bcol + r) * K + kt + cs * 8, (char*)Ws + idx * 16);
      }
    } else {
      const float* W = (const float*)Wp;
#pragma unroll
      for (int i = 0; i < 4; ++i) {
        const int idx = i * 256 + tid;
        const int r = idx >> 3, c = idx & 7;
        const float* wp = W + (size_t)(bcol + r) * K + kt + c * 8;
        const f32x4 lo = *(const f32x4*)wp;
        const f32x4 hi = *(const f32x4*)(wp + 4);
        s16x8 o;
#pragma unroll
        for (int j = 0; j < 4; ++j) {
          o[j]     = (short)f2bf(lo[j]);
          o[4 + j] = (short)f2bf(hi[j]);
        }
        *(s16x8*)((char*)Ws + (size_t)(r * 8 + (c ^ (r & 7))) * 16) = o;  // swizzled dest
      }
    }
    __syncthreads();
#pragma unroll
    for (int kk = 0; kk < 2; ++kk) {
      s16x8 af[4], bf[4];
#pragma unroll
      for (int m = 0; m < 4; ++m) {
        const int row = wr * 64 + m * 16 + li;
        af[m] = *(const s16x8*)&As[row * 64 + (((kk * 4 + g) ^ (li & 7)) & 7) * 8];
      }
#pragma unroll
      for (int n = 0; n < 4; ++n) {
        const int row = wc * 64 + n * 16 + li;
        bf[n] = *(const s16x8*)&Ws[row * 64 + (((kk * 4 + g) ^ (li & 7)) & 7) * 8];
      }
#pragma unroll
      for (int m = 0; m < 4; ++m)
#pragma unroll
        for (int n = 0; n < 4; ++n)
          acc[m][n] = mfma16(af[m], bf[n], acc[m][n]);
    }
    __syncthreads();
  }

#pragma unroll
  for (int m = 0; m < 4; ++m) {
#pragma unroll
    for (int n = 0; n < 4; ++n) {
      const int col = bcol + wc * 64 + n * 16 + li;
      const float bv = bias[col];
#pragma unroll
      for (int r = 0; r < 4; ++r) {
        const int row = brow + wr * 64 + m * 16 + g * 4 + r;
        const float v = acc[m][n][r] + bv;
        if (EPI == 0) {
          ((short*)outp)[(size_t)row * N + col] = (short)f2bf(v);
        } else {
          const size_t o = (size_t)row * N + col;
          ((float*)outp)[o] = v + resid[o];
        }
      }
    }
  }
}

// ---------------------------------------------------------------------------
// Flash attention R5.  Grid (L/64, nbatch*H), block = 128 thr = 2 waves.
// Each wave owns 32 q rows (mq = 0,1 sixteen-row frag blocks).  KVBLK=64,
// double-buffered K (XOR-swizzled) and V (tr-subtiled) via global_load_lds.
// Swapped QK^T: S^T = mfma(K, Q) -> lane (g,li) holds S[kv=n*16+g*4+r][q=mq*16+li].
// Softmax per-lane (q = mq*16+li), reduce via shfl16 + permlane32.
// P: b64 pack -> swizzled per-wave LDS -> b128 A-frags (kv-b128-block XOR li&7).
// V: ds_read_b64_tr_b16, per-lane addr base + (l>>4)*256 + (l&15)*2.
// ---------------------------------------------------------------------------
#define TRRD(dst, addr, OFF)                                                   \
  asm volatile("ds_read_b64_tr_b16 %0, %1 offset:" #OFF                        \
               : "=v"(dst) : "v"(addr))

__global__ __launch_bounds__(128) void attn_kernel(const short* __restrict__ qkv,
                                                   short* __restrict__ obuf) {
  __shared__ __align__(16) short Ks[2][64 * 64];
  __shared__ __align__(16) short Vt[2][64 * 64];
  __shared__ __align__(16) short Ps[2][32 * 64];
  const int tid  = threadIdx.x;
  const int lane = tid & 63, w = tid >> 6;
  const int g = lane >> 4, li = lane & 15;
  const int bh = blockIdx.y;
  const int b = bh / Hh, h = bh % Hh;
  const size_t rowbase = (size_t)b * Ll * N1;
  const int q0 = blockIdx.x * 64 + w * 32;
  constexpr float kScale = 0.125f * 1.44269504f;  // 1/sqrt(Dh) * log2(e)

  // Q fragments (B operand of swapped QK^T), 2 sixteen-row blocks
  s16x8 qf[2][2];
#pragma unroll
  for (int mq = 0; mq < 2; ++mq)
#pragma unroll
    for (int ks = 0; ks < 2; ++ks)
      qf[mq][ks] = *(const s16x8*)(qkv + rowbase + (size_t)(q0 + mq * 16 + li) * N1 +
                                   h * Dh + ks * 32 + g * 8);

  f32x4 oa[2][4];
  float m_[2] = {-1e30f, -1e30f}, l_[2] = {0.f, 0.f};   // per-lane: q = mq*16+li
#pragma unroll
  for (int mq = 0; mq < 2; ++mq)
#pragma unroll
    for (int dn = 0; dn < 4; ++dn)
#pragma unroll
      for (int r = 0; r < 4; ++r) oa[mq][dn][r] = 0.f;

  constexpr int NT = Ll / 64;  // 32 tiles

  // ---- staging helpers (dest lane-linear; structure in SOURCE addr) ----
  auto stageK = [&](int t, int buf) {
    const size_t kb = rowbase + (size_t)t * 64 * N1 + Dd + h * Dh;
#pragma unroll
    for (int i = 0; i < 4; ++i) {
      const int idx = i * 128 + tid;
      const int r = idx >> 3, c = idx & 7;
      gload_lds16(qkv + kb + (size_t)r * N1 + (c ^ (r & 7)) * 8,
                  (char*)&Ks[buf][0] + idx * 16);
    }
  };
  auto stageV = [&](int t, int buf) {
    const size_t kb = rowbase + (size_t)t * 64 * N1 + 2 * Dd + h * Dh;
#pragma unroll
    for (int i = 0; i < 4; ++i) {
      const int idx = i * 128 + tid;
      const int T  = idx >> 3;
      const int kv = (T & 15) * 4 + ((idx & 7) >> 1);
      const int d0 = (T >> 4) * 16 + (idx & 1) * 8;
      gload_lds16(qkv + kb + (size_t)kv * N1 + d0, (char*)&Vt[buf][0] + idx * 16);
    }
  };

  stageK(0, 0);
  stageV(0, 0);
  __syncthreads();

  for (int kt = 0; kt < NT; ++kt) {
    const int cur = kt & 1;
    if (kt + 1 < NT) {
      stageK(kt + 1, cur ^ 1);
      stageV(kt + 1, cur ^ 1);
    }

    // ---- S^T = mfma(K, Q) * scale (exp2 domain) ----
    f32x4 s[2][4];
#pragma unroll
    for (int n = 0; n < 4; ++n) {
      const int row = n * 16 + li;
      s16x8 kf0 = *(const s16x8*)&Ks[cur][row * 64 + ((g ^ (li & 7)) & 7) * 8];
      s16x8 kf1 = *(const s16x8*)&Ks[cur][row * 64 + (((4 + g) ^ (li & 7)) & 7) * 8];
#pragma unroll
      for (int mq = 0; mq < 2; ++mq) {
        f32x4 z;
#pragma unroll
        for (int r = 0; r < 4; ++r) z[r] = 0.f;
        z = mfma16(kf0, qf[mq][0], z);
        z = mfma16(kf1, qf[mq][1], z);
#pragma unroll
        for (int r = 0; r < 4; ++r) s[mq][n][r] = z[r] * kScale;
      }
    }

    // ---- online softmax per mq (lane's q = mq*16+li) ----
    float sc[2];
#pragma unroll
    for (int mq = 0; mq < 2; ++mq) {
      float mx = fmaxf(fmaxf(fmaxf(s[mq][0][0], s[mq][0][1]), fmaxf(s[mq][0][2], s[mq][0][3])),
                       fmaxf(fmaxf(s[mq][1][0], s[mq][1][1]), fmaxf(s[mq][1][2], s[mq][1][3])));
      mx = fmaxf(mx, fmaxf(fmaxf(fmaxf(s[mq][2][0], s[mq][2][1]), fmaxf(s[mq][2][2], s[mq][2][3])),
                           fmaxf(fmaxf(s[mq][3][0], s[mq][3][1]), fmaxf(s[mq][3][2], s[mq][3][3]))));
      mx = redmax64(mx);
      const float mnew = fmaxf(m_[mq], mx);
      sc[mq] = exp2f(m_[mq] - mnew);
      float rs = 0.f;
#pragma unroll
      for (int n = 0; n < 4; ++n)
#pragma unroll
        for (int r = 0; r < 4; ++r) {
          s[mq][n][r] = exp2f(s[mq][n][r] - mnew);
          rs += s[mq][n][r];
        }
      rs = redsum64(rs);
      l_[mq] = l_[mq] * sc[mq] + rs;
      m_[mq] = mnew;
    }

    // ---- rescale oa by sc of its q-row (q = mq*16 + g*4 + r) ----
#pragma unroll
    for (int mq = 0; mq < 2; ++mq) {
      float scq[4];
#pragma unroll
      for (int r = 0; r < 4; ++r)
        scq[r] = __shfl(sc[mq], (lane & 48) + g * 4 + r, 64);
#pragma unroll
      for (int dn = 0; dn < 4; ++dn)
#pragma unroll
        for (int r = 0; r < 4; ++r) oa[mq][dn][r] *= scq[r];
    }

    // ---- P pack -> swizzled per-wave LDS (8 x ds_write_b64) ----
    {
      char* Pb = (char*)&Ps[w][0];
#pragma unroll
      for (int mq = 0; mq < 2; ++mq)
#pragma unroll
        for (int n = 0; n < 4; ++n) {
          const unsigned u0 = (unsigned)f2bf(s[mq][n][0]) | ((unsigned)f2bf(s[mq][n][1]) << 16);
          const unsigned u1 = (unsigned)f2bf(s[mq][n][2]) | ((unsigned)f2bf(s[mq][n][3]) << 16);
          i32x2 pv; pv[0] = (int)u0; pv[1] = (int)u1;
          const int off = (mq * 16 + li) * 128 +
                          (((2 * n + (g >> 1)) ^ (li & 7)) << 4) + 8 * (g & 1);
          *(i32x2*)(Pb + off) = pv;
        }
    }

    // ---- P A-frag reads (4 x b128) ----
    s16x8 pf[2][2];
#pragma unroll
    for (int mq = 0; mq < 2; ++mq)
#pragma unroll
      for (int kk = 0; kk < 2; ++kk)
        pf[mq][kk] = *(const s16x8*)((char*)&Ps[w][0] + (mq * 16 + li) * 128 +
                                     (((4 * kk + g) ^ (li & 7)) << 4));

    // ---- V^T fragments via HW transpose reads (16 x ds_read_b64_tr_b16) ----
    union VU { long l[2]; s16x8 v; };
    VU vu[4][2];
    {
      const unsigned vaddr = (unsigned)(unsigned long long)(&Vt[cur][0]) +
                             (unsigned)((lane >> 4) * 256 + (lane & 15) * 2);
      TRRD(vu[0][0].l[0], vaddr, 0);    TRRD(vu[0][0].l[1], vaddr, 128);
      TRRD(vu[0][1].l[0], vaddr, 1024); TRRD(vu[0][1].l[1], vaddr, 1152);
      TRRD(vu[1][0].l[0], vaddr, 2048); TRRD(vu[1][0].l[1], vaddr, 2176);
      TRRD(vu[1][1].l[0], vaddr, 3072); TRRD(vu[1][1].l[1], vaddr, 3200);
      TRRD(vu[2][0].l[0], vaddr, 4096); TRRD(vu[2][0].l[1], vaddr, 4224);
      TRRD(vu[2][1].l[0], vaddr, 5120); TRRD(vu[2][1].l[1], vaddr, 5248);
      TRRD(vu[3][0].l[0], vaddr, 6144); TRRD(vu[3][0].l[1], vaddr, 6272);
      TRRD(vu[3][1].l[0], vaddr, 7168); TRRD(vu[3][1].l[1], vaddr, 7296);
    }
    asm volatile("s_waitcnt lgkmcnt(0)" ::: "memory");
    __builtin_amdgcn_sched_barrier(0);

    // ---- O += P V ----
#pragma unroll
    for (int mq = 0; mq < 2; ++mq)
#pragma unroll
      for (int dn = 0; dn < 4; ++dn) {
        oa[mq][dn] = mfma16(pf[mq][0], vu[dn][0].v, oa[mq][dn]);
        oa[mq][dn] = mfma16(pf[mq][1], vu[dn][1].v, oa[mq][dn]);
      }
    __syncthreads();
  }

  // ---- O / l -> bf16 obuf (row q = q0 + mq*16 + g*4 + r) ----
#pragma unroll
  for (int mq = 0; mq < 2; ++mq)
#pragma unroll
    for (int r = 0; r < 4; ++r) {
      const float lq = __shfl(l_[mq], (lane & 48) + g * 4 + r, 64);
      const float inv = 1.f / lq;
      const int row = b * Ll + q0 + mq * 16 + g * 4 + r;
#pragma unroll
      for (int dn = 0; dn < 4; ++dn)
        obuf[(size_t)row * Dd + h * Dh + dn * 16 + li] =
            (short)f2bf(oa[mq][dn][r] * inv);
    }
}

// ---------------------------------------------------------------------------
extern "C" void kernel_launch(void* const* d_in, const int* in_sizes, int n_in,
                              void* d_out, int out_size, void* d_ws, size_t ws_size,
                              hipStream_t stream) {
  const float* x     = (const float*)d_in[0];
  const float* gamma = (const float*)d_in[1];
  const float* beta  = (const float*)d_in[2];
  const float* w1    = (const float*)d_in[3];
  const float* b1    = (const float*)d_in[4];
  const float* w2    = (const float*)d_in[5];
  const float* b2    = (const float*)d_in[6];
  float* out = (float*)d_out;
  char* ws = (char*)d_ws;

  if (ws_size >= 29884416) {
    // ---- T1: full batch in one pass.  ws = 29,884,416 B ----
    short* qkvb = (short*)(ws);              // 4096*2304*2 = 18874368
    short* hb   = (short*)(ws + 18874368);   // 4096*768*2  = 6291456 (hbuf, then obuf)
    short* w1b  = (short*)(ws + 25165824);   // 2304*768*2  = 3538944
    short* w2b  = (short*)(ws + 28704768);   // 768*768*2   = 1179648
    ln_kernel<<<dim3(Mrows), dim3(256), 0, stream>>>(x, gamma, beta, hb);
    cvt_kernel<<<dim3(1024), dim3(256), 0, stream>>>(w1, w2, w1b, w2b);
    gemm_bt<0, 0><<<dim3(N1 / 128, Mrows / 128), dim3(256), 0, stream>>>(
        hb, w1b, b1, nullptr, (void*)qkvb, N1, Dd);
    attn_kernel<<<dim3(Ll / 64, Bb * Hh), dim3(128), 0, stream>>>(qkvb, hb);
    gemm_bt<1, 0><<<dim3(Dd / 128, Mrows / 128), dim3(256), 0, stream>>>(
        hb, w2b, b2, x, (void*)out, Dd, Dd);
  } else if (ws_size >= 17301504) {
    // ---- T2: per-batch, bf16 weights.  ws = 17,301,504 B ----
    short* qkvb = (short*)(ws);              // 2048*2304*2 = 9437184
    short* hb   = (short*)(ws + 9437184);    // 2048*768*2  = 3145728 (hbuf/obuf)
    short* w1b  = (short*)(ws + 12582912);   // 3538944
    short* w2b  = (short*)(ws + 16121856);   // 1179648
    cvt_kernel<<<dim3(1024), dim3(256), 0, stream>>>(w1, w2, w1b, w2b);
    for (int b = 0; b < Bb; ++b) {
      const size_t ro = (size_t)b * Ll * Dd;
      ln_kernel<<<dim3(Ll), dim3(256), 0, stream>>>(x + ro, gamma, beta, hb);
      gemm_bt<0, 0><<<dim3(N1 / 128, Ll / 128), dim3(256), 0, stream>>>(
          hb, w1b, b1, nullptr, (void*)qkvb, N1, Dd);
      attn_kernel<<<dim3(Ll / 64, Hh), dim3(128), 0, stream>>>(qkvb, hb);
      gemm_bt<1, 0><<<dim3(Dd / 128, Ll / 128), dim3(256), 0, stream>>>(
          hb, w2b, b2, x + ro, (void*)(out + ro), Dd, Dd);
    }
  } else {
    // ---- T3: per-batch, fp32 weights staged on the fly.  ws = 12,582,912 B ----
    short* qkvb = (short*)(ws);              // 9437184
    short* hb   = (short*)(ws + 9437184);    // 3145728 (hbuf/obuf)
    for (int b = 0; b < Bb; ++b) {
      const size_t ro = (size_t)b * Ll * Dd;
      ln_kernel<<<dim3(Ll), dim3(256), 0, stream>>>(x + ro, gamma, beta, hb);
      gemm_bt<0, 1><<<dim3(N1 / 128, Ll / 128), dim3(256), 0, stream>>>(
          hb, w1, b1, nullptr, (void*)qkvb, N1, Dd);
      attn_kernel<<<dim3(Ll / 64, Hh), dim3(128), 0, stream>>>(qkvb, hb);
      gemm_bt<1, 1><<<dim3(Dd / 128, Ll / 128), dim3(256), 0, stream>>>(
          hb, w2, b2, x + ro, (void*)(out + ro), Dd, Dd);
    }
  }
}

// Round 7
// 137.541 us; speedup vs baseline: 1.1950x; 1.1950x over previous
//
#include <hip/hip_runtime.h>

// ---------------------------------------------------------------------------
// Fused pre-LN MHA block on MI355X (gfx950).
// B=2, L=2048, D=768, H=12, Dh=64.  All matmuls via mfma_f32_16x16x32_bf16.
// Pipeline: LN -> (cvt weights) -> GEMM1 (qkv) -> flash-attn -> GEMM2+residual
// R6: attn reverted to R4 structure (4 waves x 16 q, 256 thr, 12 waves/CU) +
// cvt_pk P-pack, defer-max (THR=8, wave-uniform skip), hoisted staging
// pointers and LDS fragment offsets, permlane32 reduces.
// ---------------------------------------------------------------------------

#define DEV __device__ __forceinline__

typedef __attribute__((ext_vector_type(4))) float f32x4;
typedef __attribute__((ext_vector_type(8))) short s16x8;
typedef __attribute__((ext_vector_type(2))) int i32x2;

constexpr int Bb   = 2;
constexpr int Ll   = 2048;
constexpr int Dd   = 768;
constexpr int Hh   = 12;
constexpr int Dh   = 64;
constexpr int Mrows = Bb * Ll;      // 4096
constexpr int N1   = 3 * Dd;        // 2304

DEV unsigned short f2bf(float f) {
  union { float f; unsigned u; } v; v.f = f;
  unsigned r = v.u + 0x7fffu + ((v.u >> 16) & 1u);
  return (unsigned short)(r >> 16);
}

DEV void gload_lds16(const void* g, void* l) {
  __builtin_amdgcn_global_load_lds((const __attribute__((address_space(1))) unsigned int*)g,
                                   (__attribute__((address_space(3))) unsigned int*)l,
                                   16, 0, 0);
}

DEV f32x4 mfma16(s16x8 a, s16x8 b, f32x4 c) {
  return __builtin_amdgcn_mfma_f32_16x16x32_bf16(a, b, c, 0, 0, 0);
}

// reduce over lanes {l, l^16, l^32, l^48}: shfl for xor16, permlane32 for xor32
DEV float redmax64(float x) {
  x = fmaxf(x, __shfl_xor(x, 16, 64));
  float a = x, b = x;
  asm volatile("v_permlane32_swap_b32 %0, %1" : "+v"(a), "+v"(b));
  return fmaxf(a, b);
}
DEV float redsum64(float x) {
  x += __shfl_xor(x, 16, 64);
  float a = x, b = x;
  asm volatile("v_permlane32_swap_b32 %0, %1" : "+v"(a), "+v"(b));
  return a + b;
}

// ---------------------------------------------------------------------------
// Kernel 1: LayerNorm fp32 -> bf16.  One block per row (768 elems, 256 thr).
// ---------------------------------------------------------------------------
__global__ __launch_bounds__(256) void ln_kernel(const float* __restrict__ x,
                                                 const float* __restrict__ gamma,
                                                 const float* __restrict__ beta,
                                                 short* __restrict__ hbuf) {
  const int row = blockIdx.x, t = threadIdx.x;
  const float* xr = x + (size_t)row * Dd;
  float v0 = xr[t], v1 = xr[t + 256], v2 = xr[t + 512];
  float s = v0 + v1 + v2;
  float q = v0 * v0 + v1 * v1 + v2 * v2;
#pragma unroll
  for (int off = 32; off; off >>= 1) {
    s += __shfl_xor(s, off, 64);
    q += __shfl_xor(q, off, 64);
  }
  __shared__ float red[8];
  const int w = t >> 6, lane = t & 63;
  if (lane == 0) { red[w] = s; red[4 + w] = q; }
  __syncthreads();
  s = red[0] + red[1] + red[2] + red[3];
  q = red[4] + red[5] + red[6] + red[7];
  const float mean = s * (1.f / Dd);
  const float var  = q * (1.f / Dd) - mean * mean;
  const float rstd = rsqrtf(var + 1e-5f);
  short* hr = hbuf + (size_t)row * Dd;
  hr[t]       = (short)f2bf((v0 - mean) * rstd * gamma[t]       + beta[t]);
  hr[t + 256] = (short)f2bf((v1 - mean) * rstd * gamma[t + 256] + beta[t + 256]);
  hr[t + 512] = (short)f2bf((v2 - mean) * rstd * gamma[t + 512] + beta[t + 512]);
}

// ---------------------------------------------------------------------------
// Kernel 2: convert w1 [2304*768] and w2 [768*768] fp32 -> bf16.
// ---------------------------------------------------------------------------
constexpr int W1E = N1 * Dd;     // 1769472
constexpr int W2E = Dd * Dd;     // 589824
__global__ __launch_bounds__(256) void cvt_kernel(const float* __restrict__ w1,
                                                  const float* __restrict__ w2,
                                                  short* __restrict__ w1b,
                                                  short* __restrict__ w2b) {
  int i = blockIdx.x * 256 + threadIdx.x;
  const int stride = gridDim.x * 256;
  for (; i < W1E + W2E; i += stride) {
    if (i < W1E) w1b[i] = (short)f2bf(w1[i]);
    else         w2b[i - W1E] = (short)f2bf(w2[i - W1E]);
  }
}

// ---------------------------------------------------------------------------
// GEMM (B^T form): C[m][n] = sum_k A[m][k] * W[n][k] (+bias)(+resid)
// 128x128 tile, BK=64, 4 waves (2x2), each wave 64x64 = 4x4 16x16 frags.
// LDS tiles XOR-swizzled via pre-swizzled global source (m173 pattern).
// ---------------------------------------------------------------------------
template <int EPI, int WSRC>
__global__ __launch_bounds__(256) void gemm_bt(const short* __restrict__ A,
                                               const void* __restrict__ Wp,
                                               const float* __restrict__ bias,
                                               const float* __restrict__ resid,
                                               void* __restrict__ outp,
                                               int N, int K) {
  __shared__ __align__(16) short As[128 * 64];
  __shared__ __align__(16) short Ws[128 * 64];
  const int tid  = threadIdx.x;
  const int lane = tid & 63, wid = tid >> 6;
  const int wr = wid >> 1, wc = wid & 1;
  const int g = lane >> 4, li = lane & 15;
  const int brow = blockIdx.y * 128, bcol = blockIdx.x * 128;

  f32x4 acc[4][4];
#pragma unroll
  for (int m = 0; m < 4; ++m)
#pragma unroll
    for (int n = 0; n < 4; ++n)
#pragma unroll
      for (int r = 0; r < 4; ++r) acc[m][n][r] = 0.f;

  for (int kt = 0; kt < K; kt += 64) {
#pragma unroll
    for (int i = 0; i < 4; ++i) {
      const int idx = i * 256 + tid;
      const int r = idx >> 3, c = idx & 7;
      const int cs = c ^ (r & 7);              // pre-swizzled source block
      gload_lds16(A + (size_t)(brow + r) * K + kt + cs * 8, (char*)As + idx * 16);
    }
    if constexpr (WSRC == 0) {
      const short* W = (const short*)Wp;
#pragma unroll
      for (int i = 0; i < 4; ++i) {
        const int idx = i * 256 + tid;
        const int r = idx >> 3, c = idx & 7;
        const int cs = c ^ (r & 7);
        gload_lds16(W + (size_t)(bcol + r) * K + kt + cs * 8, (char*)Ws + idx * 16);
      }
    } else {
      const float* W = (const float*)Wp;
#pragma unroll
      for (int i = 0; i < 4; ++i) {
        const int idx = i * 256 + tid;
        const int r = idx >> 3, c = idx & 7;
        const float* wp = W + (size_t)(bcol + r) * K + kt + c * 8;
        const f32x4 lo = *(const f32x4*)wp;
        const f32x4 hi = *(const f32x4*)(wp + 4);
        s16x8 o;
#pragma unroll
        for (int j = 0; j < 4; ++j) {
          o[j]     = (short)f2bf(lo[j]);
          o[4 + j] = (short)f2bf(hi[j]);
        }
        *(s16x8*)((char*)Ws + (size_t)(r * 8 + (c ^ (r & 7))) * 16) = o;  // swizzled dest
      }
    }
    __syncthreads();
#pragma unroll
    for (int kk = 0; kk < 2; ++kk) {
      s16x8 af[4], bf[4];
#pragma unroll
      for (int m = 0; m < 4; ++m) {
        const int row = wr * 64 + m * 16 + li;
        af[m] = *(const s16x8*)&As[row * 64 + (((kk * 4 + g) ^ (li & 7)) & 7) * 8];
      }
#pragma unroll
      for (int n = 0; n < 4; ++n) {
        const int row = wc * 64 + n * 16 + li;
        bf[n] = *(const s16x8*)&Ws[row * 64 + (((kk * 4 + g) ^ (li & 7)) & 7) * 8];
      }
#pragma unroll
      for (int m = 0; m < 4; ++m)
#pragma unroll
        for (int n = 0; n < 4; ++n)
          acc[m][n] = mfma16(af[m], bf[n], acc[m][n]);
    }
    __syncthreads();
  }

#pragma unroll
  for (int m = 0; m < 4; ++m) {
#pragma unroll
    for (int n = 0; n < 4; ++n) {
      const int col = bcol + wc * 64 + n * 16 + li;
      const float bv = bias[col];
#pragma unroll
      for (int r = 0; r < 4; ++r) {
        const int row = brow + wr * 64 + m * 16 + g * 4 + r;
        const float v = acc[m][n][r] + bv;
        if (EPI == 0) {
          ((short*)outp)[(size_t)row * N + col] = (short)f2bf(v);
        } else {
          const size_t o = (size_t)row * N + col;
          ((float*)outp)[o] = v + resid[o];
        }
      }
    }
  }
}

// ---------------------------------------------------------------------------
// Flash attention R6 (= R4 structure + VALU diet).
// Grid (L/64, nbatch*H), 256 thr = 4 waves; wave owns 16 q rows.  KVBLK=64,
// double-buffered K (XOR-swizzled) + V (tr-subtiled) via global_load_lds.
// Swapped QK^T: lane (g,li) holds S[kv=n*16+g*4+r][q=li].  Per-lane softmax,
// reduce shfl16+permlane32.  Defer-max: skip rescale when max growth <= 8.
// P pack via v_cvt_pk_bf16_f32 -> swizzled LDS -> A-frag b128 reads.
// V read via ds_read_b64_tr_b16, per-lane addr base+(l>>4)*256+(l&15)*2.
// ---------------------------------------------------------------------------
#define TRRD(dst, addr, OFF)                                                   \
  asm volatile("ds_read_b64_tr_b16 %0, %1 offset:" #OFF                        \
               : "=v"(dst) : "v"(addr))

__global__ __launch_bounds__(256) void attn_kernel(const short* __restrict__ qkv,
                                                   short* __restrict__ obuf) {
  __shared__ __align__(16) short Ks[2][64 * 64];
  __shared__ __align__(16) short Vt[2][64 * 64];
  __shared__ __align__(16) short Ps[4][16 * 64];
  const int tid  = threadIdx.x;
  const int lane = tid & 63, w = tid >> 6;
  const int g = lane >> 4, li = lane & 15;
  const int bh = blockIdx.y;
  const int b = bh / Hh, h = bh % Hh;
  const size_t rowbase = (size_t)b * Ll * N1;
  const int q0 = blockIdx.x * 64 + w * 16;
  constexpr float kScale = 0.125f * 1.44269504f;  // 1/sqrt(Dh) * log2(e)
  constexpr int KVSTRIDE = 64 * N1;               // elements per KV tile

  // Q fragments (B operand of swapped QK^T)
  s16x8 qf[2];
#pragma unroll
  for (int ks = 0; ks < 2; ++ks)
    qf[ks] = *(const s16x8*)(qkv + rowbase + (size_t)(q0 + li) * N1 +
                             h * Dh + ks * 32 + g * 8);

  f32x4 oa[4];
  float m_ = -1e30f, l_ = 0.f;   // per-lane: q = li
#pragma unroll
  for (int dn = 0; dn < 4; ++dn)
#pragma unroll
    for (int r = 0; r < 4; ++r) oa[dn][r] = 0.f;

  constexpr int NT = Ll / 64;  // 32 tiles

  // ---- hoisted staging source pointers (advance by KVSTRIDE per tile) ----
  const int ia = tid, ib = 256 + tid;
  const int ra = ia >> 3, ca = ia & 7, rb = ib >> 3, cb = ib & 7;
  const short* kpa = qkv + rowbase + Dd + h * Dh + (size_t)ra * N1 + (ca ^ (ra & 7)) * 8;
  const short* kpb = qkv + rowbase + Dd + h * Dh + (size_t)rb * N1 + (cb ^ (rb & 7)) * 8;
  const int Ta = ia >> 3, Tb = ib >> 3;
  const short* vpa = qkv + rowbase + 2 * Dd + h * Dh +
                     (size_t)((Ta & 15) * 4 + (ca >> 1)) * N1 + (Ta >> 4) * 16 + (ia & 1) * 8;
  const short* vpb = qkv + rowbase + 2 * Dd + h * Dh +
                     (size_t)((Tb & 15) * 4 + (cb >> 1)) * N1 + (Tb >> 4) * 16 + (ib & 1) * 8;
  char* KsB = (char*)&Ks[0][0];
  char* VtB = (char*)&Vt[0][0];
  const int dsta = ia * 16, dstb = ib * 16;

  // ---- hoisted LDS fragment offsets (bytes) ----
  int koff[4][2];
#pragma unroll
  for (int n = 0; n < 4; ++n) {
    koff[n][0] = ((n * 16 + li) * 64 + ((g ^ (li & 7)) & 7) * 8) * 2;
    koff[n][1] = ((n * 16 + li) * 64 + (((4 + g) ^ (li & 7)) & 7) * 8) * 2;
  }
  int pwoff[4], proff[2];
#pragma unroll
  for (int n = 0; n < 4; ++n)
    pwoff[n] = li * 128 + (((2 * n + (g >> 1)) ^ (li & 7)) << 4) + 8 * (g & 1);
#pragma unroll
  for (int kk = 0; kk < 2; ++kk)
    proff[kk] = li * 128 + (((4 * kk + g) ^ (li & 7)) << 4);
  char* Pw = (char*)&Ps[w][0];
  const unsigned vlane = (unsigned)((lane >> 4) * 256 + (lane & 15) * 2);
  const unsigned vbase0 = (unsigned)(unsigned long long)(&Vt[0][0]) + vlane;

  auto stage = [&](int buf) {
    const int bo = buf << 13;
    gload_lds16(kpa, KsB + bo + dsta);
    gload_lds16(kpb, KsB + bo + dstb);
    gload_lds16(vpa, VtB + bo + dsta);
    gload_lds16(vpb, VtB + bo + dstb);
    kpa += KVSTRIDE; kpb += KVSTRIDE; vpa += KVSTRIDE; vpb += KVSTRIDE;
  };

  stage(0);
  __syncthreads();

  for (int kt = 0; kt < NT; ++kt) {
    const int cur = kt & 1;
    if (kt + 1 < NT) stage(cur ^ 1);
    const int curo = cur << 13;

    // ---- S^T = mfma(K, Q) * scale (exp2 domain) ----
    f32x4 s[4];
#pragma unroll
    for (int n = 0; n < 4; ++n) {
      s16x8 kf0 = *(const s16x8*)(KsB + curo + koff[n][0]);
      s16x8 kf1 = *(const s16x8*)(KsB + curo + koff[n][1]);
      f32x4 z;
#pragma unroll
      for (int r = 0; r < 4; ++r) z[r] = 0.f;
      z = mfma16(kf0, qf[0], z);
      z = mfma16(kf1, qf[1], z);
#pragma unroll
      for (int r = 0; r < 4; ++r) s[n][r] = z[r] * kScale;
    }

    // ---- online softmax with defer-max (per-lane q = li) ----
    float mx = fmaxf(fmaxf(fmaxf(s[0][0], s[0][1]), fmaxf(s[0][2], s[0][3])),
                     fmaxf(fmaxf(s[1][0], s[1][1]), fmaxf(s[1][2], s[1][3])));
    mx = fmaxf(mx, fmaxf(fmaxf(fmaxf(s[2][0], s[2][1]), fmaxf(s[2][2], s[2][3])),
                         fmaxf(fmaxf(s[3][0], s[3][1]), fmaxf(s[3][2], s[3][3]))));
    mx = redmax64(mx);
    if (!__all(mx - m_ <= 8.f)) {
      const float mnew = fmaxf(m_, mx);
      const float sc = exp2f(m_ - mnew);
      float scq[4];
#pragma unroll
      for (int r = 0; r < 4; ++r)
        scq[r] = __shfl(sc, (lane & 48) + ((lane & 48) >> 2) + r, 64);
#pragma unroll
      for (int dn = 0; dn < 4; ++dn)
#pragma unroll
        for (int r = 0; r < 4; ++r) oa[dn][r] *= scq[r];
      l_ *= sc;
      m_ = mnew;
    }
    float rs = 0.f;
#pragma unroll
    for (int n = 0; n < 4; ++n)
#pragma unroll
      for (int r = 0; r < 4; ++r) {
        s[n][r] = exp2f(s[n][r] - m_);
        rs += s[n][r];
      }
    rs = redsum64(rs);
    l_ += rs;

    // ---- P pack via cvt_pk -> swizzled per-wave LDS (4 x ds_write_b64) ----
#pragma unroll
    for (int n = 0; n < 4; ++n) {
      unsigned u0, u1;
      asm("v_cvt_pk_bf16_f32 %0, %1, %2" : "=v"(u0) : "v"(s[n][0]), "v"(s[n][1]));
      asm("v_cvt_pk_bf16_f32 %0, %1, %2" : "=v"(u1) : "v"(s[n][2]), "v"(s[n][3]));
      i32x2 pv; pv[0] = (int)u0; pv[1] = (int)u1;
      *(i32x2*)(Pw + pwoff[n]) = pv;
    }

    // ---- P A-frag reads (2 x b128) ----
    s16x8 pf[2];
#pragma unroll
    for (int kk = 0; kk < 2; ++kk)
      pf[kk] = *(const s16x8*)(Pw + proff[kk]);

    // ---- V^T fragments via HW transpose reads (16 x ds_read_b64_tr_b16) ----
    union VU { long l[2]; s16x8 v; };
    VU vu[4][2];
    {
      const unsigned vaddr = vbase0 + (unsigned)curo;
      TRRD(vu[0][0].l[0], vaddr, 0);    TRRD(vu[0][0].l[1], vaddr, 128);
      TRRD(vu[0][1].l[0], vaddr, 1024); TRRD(vu[0][1].l[1], vaddr, 1152);
      TRRD(vu[1][0].l[0], vaddr, 2048); TRRD(vu[1][0].l[1], vaddr, 2176);
      TRRD(vu[1][1].l[0], vaddr, 3072); TRRD(vu[1][1].l[1], vaddr, 3200);
      TRRD(vu[2][0].l[0], vaddr, 4096); TRRD(vu[2][0].l[1], vaddr, 4224);
      TRRD(vu[2][1].l[0], vaddr, 5120); TRRD(vu[2][1].l[1], vaddr, 5248);
      TRRD(vu[3][0].l[0], vaddr, 6144); TRRD(vu[3][0].l[1], vaddr, 6272);
      TRRD(vu[3][1].l[0], vaddr, 7168); TRRD(vu[3][1].l[1], vaddr, 7296);
    }
    asm volatile("s_waitcnt lgkmcnt(0)" ::: "memory");
    __builtin_amdgcn_sched_barrier(0);

    // ---- O += P V ----
#pragma unroll
    for (int dn = 0; dn < 4; ++dn) {
      oa[dn] = mfma16(pf[0], vu[dn][0].v, oa[dn]);
      oa[dn] = mfma16(pf[1], vu[dn][1].v, oa[dn]);
    }
    __syncthreads();
  }

  // ---- O / l -> bf16 obuf (row q = q0 + g*4 + r) ----
  {
#pragma unroll
    for (int r = 0; r < 4; ++r) {
      const float lq = __shfl(l_, (lane & 48) + ((lane & 48) >> 2) + r, 64);
      const float inv = 1.f / lq;
      const int row = b * Ll + q0 + g * 4 + r;
#pragma unroll
      for (int dn = 0; dn < 4; ++dn)
        obuf[(size_t)row * Dd + h * Dh + dn * 16 + li] =
            (short)f2bf(oa[dn][r] * inv);
    }
  }
}

// ---------------------------------------------------------------------------
extern "C" void kernel_launch(void* const* d_in, const int* in_sizes, int n_in,
                              void* d_out, int out_size, void* d_ws, size_t ws_size,
                              hipStream_t stream) {
  const float* x     = (const float*)d_in[0];
  const float* gamma = (const float*)d_in[1];
  const float* beta  = (const float*)d_in[2];
  const float* w1    = (const float*)d_in[3];
  const float* b1    = (const float*)d_in[4];
  const float* w2    = (const float*)d_in[5];
  const float* b2    = (const float*)d_in[6];
  float* out = (float*)d_out;
  char* ws = (char*)d_ws;

  if (ws_size >= 29884416) {
    // ---- T1: full batch in one pass.  ws = 29,884,416 B ----
    short* qkvb = (short*)(ws);              // 4096*2304*2 = 18874368
    short* hb   = (short*)(ws + 18874368);   // 4096*768*2  = 6291456 (hbuf, then obuf)
    short* w1b  = (short*)(ws + 25165824);   // 2304*768*2  = 3538944
    short* w2b  = (short*)(ws + 28704768);   // 768*768*2   = 1179648
    ln_kernel<<<dim3(Mrows), dim3(256), 0, stream>>>(x, gamma, beta, hb);
    cvt_kernel<<<dim3(1024), dim3(256), 0, stream>>>(w1, w2, w1b, w2b);
    gemm_bt<0, 0><<<dim3(N1 / 128, Mrows / 128), dim3(256), 0, stream>>>(
        hb, w1b, b1, nullptr, (void*)qkvb, N1, Dd);
    attn_kernel<<<dim3(Ll / 64, Bb * Hh), dim3(256), 0, stream>>>(qkvb, hb);
    gemm_bt<1, 0><<<dim3(Dd / 128, Mrows / 128), dim3(256), 0, stream>>>(
        hb, w2b, b2, x, (void*)out, Dd, Dd);
  } else if (ws_size >= 17301504) {
    // ---- T2: per-batch, bf16 weights.  ws = 17,301,504 B ----
    short* qkvb = (short*)(ws);              // 2048*2304*2 = 9437184
    short* hb   = (short*)(ws + 9437184);    // 2048*768*2  = 3145728 (hbuf/obuf)
    short* w1b  = (short*)(ws + 12582912);   // 3538944
    short* w2b  = (short*)(ws + 16121856);   // 1179648
    cvt_kernel<<<dim3(1024), dim3(256), 0, stream>>>(w1, w2, w1b, w2b);
    for (int b = 0; b < Bb; ++b) {
      const size_t ro = (size_t)b * Ll * Dd;
      ln_kernel<<<dim3(Ll), dim3(256), 0, stream>>>(x + ro, gamma, beta, hb);
      gemm_bt<0, 0><<<dim3(N1 / 128, Ll / 128), dim3(256), 0, stream>>>(
          hb, w1b, b1, nullptr, (void*)qkvb, N1, Dd);
      attn_kernel<<<dim3(Ll / 64, Hh), dim3(256), 0, stream>>>(qkvb, hb);
      gemm_bt<1, 0><<<dim3(Dd / 128, Ll / 128), dim3(256), 0, stream>>>(
          hb, w2b, b2, x + ro, (void*)(out + ro), Dd, Dd);
    }
  } else {
    // ---- T3: per-batch, fp32 weights staged on the fly.  ws = 12,582,912 B ----
    short* qkvb = (short*)(ws);              // 9437184
    short* hb   = (short*)(ws + 9437184);    // 3145728 (hbuf/obuf)
    for (int b = 0; b < Bb; ++b) {
      const size_t ro = (size_t)b * Ll * Dd;
      ln_kernel<<<dim3(Ll), dim3(256), 0, stream>>>(x + ro, gamma, beta, hb);
      gemm_bt<0, 1><<<dim3(N1 / 128, Ll / 128), dim3(256), 0, stream>>>(
          hb, w1, b1, nullptr, (void*)qkvb, N1, Dd);
      attn_kernel<<<dim3(Ll / 64, Hh), dim3(256), 0, stream>>>(qkvb, hb);
      gemm_bt<1, 1><<<dim3(Dd / 128, Ll / 128), dim3(256), 0, stream>>>(
          hb, w2, b2, x + ro, (void*)(out + ro), Dd, Dd);
    }
  }
}

// Round 8
// 135.767 us; speedup vs baseline: 1.2106x; 1.0131x over previous
//
#include <hip/hip_runtime.h>

// ---------------------------------------------------------------------------
// Fused pre-LN MHA block on MI355X (gfx950).
// B=2, L=2048, D=768, H=12, Dh=64.  All matmuls via mfma_f32_16x16x32_bf16.
// Pipeline: prep(LN+cvt) -> GEMM1 (qkv) -> flash-attn -> GEMM2+residual
// R7: attn VALU diet — raw-domain running max (defer THR in raw units),
// p = exp2(fma(z,kScale,-m*kScale)) (kills 16 muls + 16 subs -> 16 FMA),
// max3-shaped reduce tree; ln+cvt fused into one prep kernel (T1 path).
// ---------------------------------------------------------------------------

#define DEV __device__ __forceinline__

typedef __attribute__((ext_vector_type(4))) float f32x4;
typedef __attribute__((ext_vector_type(8))) short s16x8;
typedef __attribute__((ext_vector_type(2))) int i32x2;

constexpr int Bb   = 2;
constexpr int Ll   = 2048;
constexpr int Dd   = 768;
constexpr int Hh   = 12;
constexpr int Dh   = 64;
constexpr int Mrows = Bb * Ll;      // 4096
constexpr int N1   = 3 * Dd;        // 2304

DEV unsigned short f2bf(float f) {
  union { float f; unsigned u; } v; v.f = f;
  unsigned r = v.u + 0x7fffu + ((v.u >> 16) & 1u);
  return (unsigned short)(r >> 16);
}

DEV void gload_lds16(const void* g, void* l) {
  __builtin_amdgcn_global_load_lds((const __attribute__((address_space(1))) unsigned int*)g,
                                   (__attribute__((address_space(3))) unsigned int*)l,
                                   16, 0, 0);
}

DEV f32x4 mfma16(s16x8 a, s16x8 b, f32x4 c) {
  return __builtin_amdgcn_mfma_f32_16x16x32_bf16(a, b, c, 0, 0, 0);
}

// reduce over lanes {l, l^16, l^32, l^48}: shfl for xor16, permlane32 for xor32
DEV float redmax64(float x) {
  x = fmaxf(x, __shfl_xor(x, 16, 64));
  float a = x, b = x;
  asm volatile("v_permlane32_swap_b32 %0, %1" : "+v"(a), "+v"(b));
  return fmaxf(a, b);
}
DEV float redsum64(float x) {
  x += __shfl_xor(x, 16, 64);
  float a = x, b = x;
  asm volatile("v_permlane32_swap_b32 %0, %1" : "+v"(a), "+v"(b));
  return a + b;
}

// ---------------------------------------------------------------------------
// LN body (one block per row, 256 thr) — used by prep_kernel and ln_kernel.
// ---------------------------------------------------------------------------
DEV void ln_body(int row, int t, const float* __restrict__ x,
                 const float* __restrict__ gamma, const float* __restrict__ beta,
                 short* __restrict__ hbuf, float* red) {
  const float* xr = x + (size_t)row * Dd;
  float v0 = xr[t], v1 = xr[t + 256], v2 = xr[t + 512];
  float s = v0 + v1 + v2;
  float q = v0 * v0 + v1 * v1 + v2 * v2;
#pragma unroll
  for (int off = 32; off; off >>= 1) {
    s += __shfl_xor(s, off, 64);
    q += __shfl_xor(q, off, 64);
  }
  const int w = t >> 6, lane = t & 63;
  if (lane == 0) { red[w] = s; red[4 + w] = q; }
  __syncthreads();
  s = red[0] + red[1] + red[2] + red[3];
  q = red[4] + red[5] + red[6] + red[7];
  const float mean = s * (1.f / Dd);
  const float var  = q * (1.f / Dd) - mean * mean;
  const float rstd = rsqrtf(var + 1e-5f);
  short* hr = hbuf + (size_t)row * Dd;
  hr[t]       = (short)f2bf((v0 - mean) * rstd * gamma[t]       + beta[t]);
  hr[t + 256] = (short)f2bf((v1 - mean) * rstd * gamma[t + 256] + beta[t + 256]);
  hr[t + 512] = (short)f2bf((v2 - mean) * rstd * gamma[t + 512] + beta[t + 512]);
}

constexpr int W1E = N1 * Dd;     // 1769472
constexpr int W2E = Dd * Dd;     // 589824

__global__ __launch_bounds__(256) void ln_kernel(const float* __restrict__ x,
                                                 const float* __restrict__ gamma,
                                                 const float* __restrict__ beta,
                                                 short* __restrict__ hbuf) {
  __shared__ float red[8];
  ln_body(blockIdx.x, threadIdx.x, x, gamma, beta, hbuf, red);
}

__global__ __launch_bounds__(256) void cvt_kernel(const float* __restrict__ w1,
                                                  const float* __restrict__ w2,
                                                  short* __restrict__ w1b,
                                                  short* __restrict__ w2b) {
  int i = blockIdx.x * 256 + threadIdx.x;
  const int stride = gridDim.x * 256;
  for (; i < W1E + W2E; i += stride) {
    if (i < W1E) w1b[i] = (short)f2bf(w1[i]);
    else         w2b[i - W1E] = (short)f2bf(w2[i - W1E]);
  }
}

// fused LN (blocks 0..Mrows-1) + weight cvt (blocks Mrows..Mrows+1023)
__global__ __launch_bounds__(256) void prep_kernel(const float* __restrict__ x,
                                                   const float* __restrict__ gamma,
                                                   const float* __restrict__ beta,
                                                   short* __restrict__ hbuf,
                                                   const float* __restrict__ w1,
                                                   const float* __restrict__ w2,
                                                   short* __restrict__ w1b,
                                                   short* __restrict__ w2b) {
  __shared__ float red[8];
  if (blockIdx.x < (unsigned)Mrows) {
    ln_body(blockIdx.x, threadIdx.x, x, gamma, beta, hbuf, red);
  } else {
    int i = (blockIdx.x - Mrows) * 256 + threadIdx.x;
    for (; i < W1E + W2E; i += 1024 * 256) {
      if (i < W1E) w1b[i] = (short)f2bf(w1[i]);
      else         w2b[i - W1E] = (short)f2bf(w2[i - W1E]);
    }
  }
}

// ---------------------------------------------------------------------------
// GEMM (B^T form): C[m][n] = sum_k A[m][k] * W[n][k] (+bias)(+resid)
// 128x128 tile, BK=64, 4 waves (2x2), each wave 64x64 = 4x4 16x16 frags.
// LDS tiles XOR-swizzled via pre-swizzled global source (m173 pattern).
// ---------------------------------------------------------------------------
template <int EPI, int WSRC>
__global__ __launch_bounds__(256) void gemm_bt(const short* __restrict__ A,
                                               const void* __restrict__ Wp,
                                               const float* __restrict__ bias,
                                               const float* __restrict__ resid,
                                               void* __restrict__ outp,
                                               int N, int K) {
  __shared__ __align__(16) short As[128 * 64];
  __shared__ __align__(16) short Ws[128 * 64];
  const int tid  = threadIdx.x;
  const int lane = tid & 63, wid = tid >> 6;
  const int wr = wid >> 1, wc = wid & 1;
  const int g = lane >> 4, li = lane & 15;
  const int brow = blockIdx.y * 128, bcol = blockIdx.x * 128;

  f32x4 acc[4][4];
#pragma unroll
  for (int m = 0; m < 4; ++m)
#pragma unroll
    for (int n = 0; n < 4; ++n)
#pragma unroll
      for (int r = 0; r < 4; ++r) acc[m][n][r] = 0.f;

  for (int kt = 0; kt < K; kt += 64) {
#pragma unroll
    for (int i = 0; i < 4; ++i) {
      const int idx = i * 256 + tid;
      const int r = idx >> 3, c = idx & 7;
      const int cs = c ^ (r & 7);              // pre-swizzled source block
      gload_lds16(A + (size_t)(brow + r) * K + kt + cs * 8, (char*)As + idx * 16);
    }
    if constexpr (WSRC == 0) {
      const short* W = (const short*)Wp;
#pragma unroll
      for (int i = 0; i < 4; ++i) {
        const int idx = i * 256 + tid;
        const int r = idx >> 3, c = idx & 7;
        const int cs = c ^ (r & 7);
        gload_lds16(W + (size_t)(bcol + r) * K + kt + cs * 8, (char*)Ws + idx * 16);
      }
    } else {
      const float* W = (const float*)Wp;
#pragma unroll
      for (int i = 0; i < 4; ++i) {
        const int idx = i * 256 + tid;
        const int r = idx >> 3, c = idx & 7;
        const float* wp = W + (size_t)(bcol + r) * K + kt + c * 8;
        const f32x4 lo = *(const f32x4*)wp;
        const f32x4 hi = *(const f32x4*)(wp + 4);
        s16x8 o;
#pragma unroll
        for (int j = 0; j < 4; ++j) {
          o[j]     = (short)f2bf(lo[j]);
          o[4 + j] = (short)f2bf(hi[j]);
        }
        *(s16x8*)((char*)Ws + (size_t)(r * 8 + (c ^ (r & 7))) * 16) = o;  // swizzled dest
      }
    }
    __syncthreads();
#pragma unroll
    for (int kk = 0; kk < 2; ++kk) {
      s16x8 af[4], bf[4];
#pragma unroll
      for (int m = 0; m < 4; ++m) {
        const int row = wr * 64 + m * 16 + li;
        af[m] = *(const s16x8*)&As[row * 64 + (((kk * 4 + g) ^ (li & 7)) & 7) * 8];
      }
#pragma unroll
      for (int n = 0; n < 4; ++n) {
        const int row = wc * 64 + n * 16 + li;
        bf[n] = *(const s16x8*)&Ws[row * 64 + (((kk * 4 + g) ^ (li & 7)) & 7) * 8];
      }
#pragma unroll
      for (int m = 0; m < 4; ++m)
#pragma unroll
        for (int n = 0; n < 4; ++n)
          acc[m][n] = mfma16(af[m], bf[n], acc[m][n]);
    }
    __syncthreads();
  }

#pragma unroll
  for (int m = 0; m < 4; ++m) {
#pragma unroll
    for (int n = 0; n < 4; ++n) {
      const int col = bcol + wc * 64 + n * 16 + li;
      const float bv = bias[col];
#pragma unroll
      for (int r = 0; r < 4; ++r) {
        const int row = brow + wr * 64 + m * 16 + g * 4 + r;
        const float v = acc[m][n][r] + bv;
        if (EPI == 0) {
          ((short*)outp)[(size_t)row * N + col] = (short)f2bf(v);
        } else {
          const size_t o = (size_t)row * N + col;
          ((float*)outp)[o] = v + resid[o];
        }
      }
    }
  }
}

// ---------------------------------------------------------------------------
// Flash attention R7 (= R6 structure + raw-domain FMA softmax + max3 tree).
// Grid (L/64, nbatch*H), 256 thr = 4 waves; wave owns 16 q rows.  KVBLK=64,
// double-buffered K (XOR-swizzled) + V (tr-subtiled) via global_load_lds.
// Swapped QK^T: lane (g,li) holds Z[kv=n*16+g*4+r][q=li] (RAW dot product).
// Running max m_ kept in RAW domain; p = exp2(fma(z,kScale,-m_*kScale)).
// Defer-max threshold 8/kScale in raw units.  P pack via v_cvt_pk_bf16_f32.
// V read via ds_read_b64_tr_b16, per-lane addr base+(l>>4)*256+(l&15)*2.
// ---------------------------------------------------------------------------
#define TRRD(dst, addr, OFF)                                                   \
  asm volatile("ds_read_b64_tr_b16 %0, %1 offset:" #OFF                        \
               : "=v"(dst) : "v"(addr))

__global__ __launch_bounds__(256) void attn_kernel(const short* __restrict__ qkv,
                                                   short* __restrict__ obuf) {
  __shared__ __align__(16) short Ks[2][64 * 64];
  __shared__ __align__(16) short Vt[2][64 * 64];
  __shared__ __align__(16) short Ps[4][16 * 64];
  const int tid  = threadIdx.x;
  const int lane = tid & 63, w = tid >> 6;
  const int g = lane >> 4, li = lane & 15;
  const int bh = blockIdx.y;
  const int b = bh / Hh, h = bh % Hh;
  const size_t rowbase = (size_t)b * Ll * N1;
  const int q0 = blockIdx.x * 64 + w * 16;
  constexpr float kScale = 0.125f * 1.44269504f;   // 1/sqrt(Dh) * log2(e)
  constexpr float kThrRaw = 8.f / kScale;          // defer-max threshold (raw)
  constexpr int KVSTRIDE = 64 * N1;                // elements per KV tile

  // Q fragments (B operand of swapped QK^T)
  s16x8 qf[2];
#pragma unroll
  for (int ks = 0; ks < 2; ++ks)
    qf[ks] = *(const s16x8*)(qkv + rowbase + (size_t)(q0 + li) * N1 +
                             h * Dh + ks * 32 + g * 8);

  f32x4 oa[4];
  float m_ = -1e30f, l_ = 0.f;   // per-lane: q = li ; m_ in RAW domain
#pragma unroll
  for (int dn = 0; dn < 4; ++dn)
#pragma unroll
    for (int r = 0; r < 4; ++r) oa[dn][r] = 0.f;

  constexpr int NT = Ll / 64;  // 32 tiles

  // ---- hoisted staging source pointers (advance by KVSTRIDE per tile) ----
  const int ia = tid, ib = 256 + tid;
  const int ra = ia >> 3, ca = ia & 7, rb = ib >> 3, cb = ib & 7;
  const short* kpa = qkv + rowbase + Dd + h * Dh + (size_t)ra * N1 + (ca ^ (ra & 7)) * 8;
  const short* kpb = qkv + rowbase + Dd + h * Dh + (size_t)rb * N1 + (cb ^ (rb & 7)) * 8;
  const int Ta = ia >> 3, Tb = ib >> 3;
  const short* vpa = qkv + rowbase + 2 * Dd + h * Dh +
                     (size_t)((Ta & 15) * 4 + (ca >> 1)) * N1 + (Ta >> 4) * 16 + (ia & 1) * 8;
  const short* vpb = qkv + rowbase + 2 * Dd + h * Dh +
                     (size_t)((Tb & 15) * 4 + (cb >> 1)) * N1 + (Tb >> 4) * 16 + (ib & 1) * 8;
  char* KsB = (char*)&Ks[0][0];
  char* VtB = (char*)&Vt[0][0];
  const int dsta = ia * 16, dstb = ib * 16;

  // ---- hoisted LDS fragment offsets (bytes) ----
  int koff[4][2];
#pragma unroll
  for (int n = 0; n < 4; ++n) {
    koff[n][0] = ((n * 16 + li) * 64 + ((g ^ (li & 7)) & 7) * 8) * 2;
    koff[n][1] = ((n * 16 + li) * 64 + (((4 + g) ^ (li & 7)) & 7) * 8) * 2;
  }
  int pwoff[4], proff[2];
#pragma unroll
  for (int n = 0; n < 4; ++n)
    pwoff[n] = li * 128 + (((2 * n + (g >> 1)) ^ (li & 7)) << 4) + 8 * (g & 1);
#pragma unroll
  for (int kk = 0; kk < 2; ++kk)
    proff[kk] = li * 128 + (((4 * kk + g) ^ (li & 7)) << 4);
  char* Pw = (char*)&Ps[w][0];
  const unsigned vlane = (unsigned)((lane >> 4) * 256 + (lane & 15) * 2);
  const unsigned vbase0 = (unsigned)(unsigned long long)(&Vt[0][0]) + vlane;

  auto stage = [&](int buf) {
    const int bo = buf << 13;
    gload_lds16(kpa, KsB + bo + dsta);
    gload_lds16(kpb, KsB + bo + dstb);
    gload_lds16(vpa, VtB + bo + dsta);
    gload_lds16(vpb, VtB + bo + dstb);
    kpa += KVSTRIDE; kpb += KVSTRIDE; vpa += KVSTRIDE; vpb += KVSTRIDE;
  };

  stage(0);
  __syncthreads();

  for (int kt = 0; kt < NT; ++kt) {
    const int cur = kt & 1;
    if (kt + 1 < NT) stage(cur ^ 1);
    const int curo = cur << 13;

    // ---- Z^T = mfma(K, Q)  (raw dot products) ----
    f32x4 s[4];
#pragma unroll
    for (int n = 0; n < 4; ++n) {
      s16x8 kf0 = *(const s16x8*)(KsB + curo + koff[n][0]);
      s16x8 kf1 = *(const s16x8*)(KsB + curo + koff[n][1]);
      f32x4 z;
#pragma unroll
      for (int r = 0; r < 4; ++r) z[r] = 0.f;
      z = mfma16(kf0, qf[0], z);
      z = mfma16(kf1, qf[1], z);
      s[n] = z;
    }

    // ---- online softmax, raw-domain max, per-lane q = li ----
    const float l0 = fmaxf(fmaxf(s[0][0], s[0][1]), s[0][2]);
    const float l1 = fmaxf(fmaxf(s[0][3], s[1][0]), s[1][1]);
    const float l2 = fmaxf(fmaxf(s[1][2], s[1][3]), s[2][0]);
    const float l3 = fmaxf(fmaxf(s[2][1], s[2][2]), s[2][3]);
    const float l4 = fmaxf(fmaxf(s[3][0], s[3][1]), s[3][2]);
    float mx = fmaxf(fmaxf(fmaxf(fmaxf(l0, l1), l2), fmaxf(l3, l4)), s[3][3]);
    mx = redmax64(mx);
    if (!__all(mx - m_ <= kThrRaw)) {
      const float mnew = fmaxf(m_, mx);
      const float sc = exp2f((m_ - mnew) * kScale);
      float scq[4];
#pragma unroll
      for (int r = 0; r < 4; ++r)
        scq[r] = __shfl(sc, (lane & 48) + ((lane & 48) >> 2) + r, 64);
#pragma unroll
      for (int dn = 0; dn < 4; ++dn)
#pragma unroll
        for (int r = 0; r < 4; ++r) oa[dn][r] *= scq[r];
      l_ *= sc;
      m_ = mnew;
    }
    const float msc = m_ * kScale;
    float rs = 0.f;
#pragma unroll
    for (int n = 0; n < 4; ++n)
#pragma unroll
      for (int r = 0; r < 4; ++r) {
        const float p = exp2f(fmaf(s[n][r], kScale, -msc));
        s[n][r] = p;
        rs += p;
      }
    rs = redsum64(rs);
    l_ += rs;

    // ---- P pack via cvt_pk -> swizzled per-wave LDS (4 x ds_write_b64) ----
#pragma unroll
    for (int n = 0; n < 4; ++n) {
      unsigned u0, u1;
      asm("v_cvt_pk_bf16_f32 %0, %1, %2" : "=v"(u0) : "v"(s[n][0]), "v"(s[n][1]));
      asm("v_cvt_pk_bf16_f32 %0, %1, %2" : "=v"(u1) : "v"(s[n][2]), "v"(s[n][3]));
      i32x2 pv; pv[0] = (int)u0; pv[1] = (int)u1;
      *(i32x2*)(Pw + pwoff[n]) = pv;
    }

    // ---- P A-frag reads (2 x b128) ----
    s16x8 pf[2];
#pragma unroll
    for (int kk = 0; kk < 2; ++kk)
      pf[kk] = *(const s16x8*)(Pw + proff[kk]);

    // ---- V^T fragments via HW transpose reads (16 x ds_read_b64_tr_b16) ----
    union VU { long l[2]; s16x8 v; };
    VU vu[4][2];
    {
      const unsigned vaddr = vbase0 + (unsigned)curo;
      TRRD(vu[0][0].l[0], vaddr, 0);    TRRD(vu[0][0].l[1], vaddr, 128);
      TRRD(vu[0][1].l[0], vaddr, 1024); TRRD(vu[0][1].l[1], vaddr, 1152);
      TRRD(vu[1][0].l[0], vaddr, 2048); TRRD(vu[1][0].l[1], vaddr, 2176);
      TRRD(vu[1][1].l[0], vaddr, 3072); TRRD(vu[1][1].l[1], vaddr, 3200);
      TRRD(vu[2][0].l[0], vaddr, 4096); TRRD(vu[2][0].l[1], vaddr, 4224);
      TRRD(vu[2][1].l[0], vaddr, 5120); TRRD(vu[2][1].l[1], vaddr, 5248);
      TRRD(vu[3][0].l[0], vaddr, 6144); TRRD(vu[3][0].l[1], vaddr, 6272);
      TRRD(vu[3][1].l[0], vaddr, 7168); TRRD(vu[3][1].l[1], vaddr, 7296);
    }
    asm volatile("s_waitcnt lgkmcnt(0)" ::: "memory");
    __builtin_amdgcn_sched_barrier(0);

    // ---- O += P V ----
#pragma unroll
    for (int dn = 0; dn < 4; ++dn) {
      oa[dn] = mfma16(pf[0], vu[dn][0].v, oa[dn]);
      oa[dn] = mfma16(pf[1], vu[dn][1].v, oa[dn]);
    }
    __syncthreads();
  }

  // ---- O / l -> bf16 obuf (row q = q0 + g*4 + r) ----
  {
#pragma unroll
    for (int r = 0; r < 4; ++r) {
      const float lq = __shfl(l_, (lane & 48) + ((lane & 48) >> 2) + r, 64);
      const float inv = 1.f / lq;
      const int row = b * Ll + q0 + g * 4 + r;
#pragma unroll
      for (int dn = 0; dn < 4; ++dn)
        obuf[(size_t)row * Dd + h * Dh + dn * 16 + li] =
            (short)f2bf(oa[dn][r] * inv);
    }
  }
}

// ---------------------------------------------------------------------------
extern "C" void kernel_launch(void* const* d_in, const int* in_sizes, int n_in,
                              void* d_out, int out_size, void* d_ws, size_t ws_size,
                              hipStream_t stream) {
  const float* x     = (const float*)d_in[0];
  const float* gamma = (const float*)d_in[1];
  const float* beta  = (const float*)d_in[2];
  const float* w1    = (const float*)d_in[3];
  const float* b1    = (const float*)d_in[4];
  const float* w2    = (const float*)d_in[5];
  const float* b2    = (const float*)d_in[6];
  float* out = (float*)d_out;
  char* ws = (char*)d_ws;

  if (ws_size >= 29884416) {
    // ---- T1: full batch in one pass.  ws = 29,884,416 B ----
    short* qkvb = (short*)(ws);              // 4096*2304*2 = 18874368
    short* hb   = (short*)(ws + 18874368);   // 4096*768*2  = 6291456 (hbuf, then obuf)
    short* w1b  = (short*)(ws + 25165824);   // 2304*768*2  = 3538944
    short* w2b  = (short*)(ws + 28704768);   // 768*768*2   = 1179648
    prep_kernel<<<dim3(Mrows + 1024), dim3(256), 0, stream>>>(
        x, gamma, beta, hb, w1, w2, w1b, w2b);
    gemm_bt<0, 0><<<dim3(N1 / 128, Mrows / 128), dim3(256), 0, stream>>>(
        hb, w1b, b1, nullptr, (void*)qkvb, N1, Dd);
    attn_kernel<<<dim3(Ll / 64, Bb * Hh), dim3(256), 0, stream>>>(qkvb, hb);
    gemm_bt<1, 0><<<dim3(Dd / 128, Mrows / 128), dim3(256), 0, stream>>>(
        hb, w2b, b2, x, (void*)out, Dd, Dd);
  } else if (ws_size >= 17301504) {
    // ---- T2: per-batch, bf16 weights.  ws = 17,301,504 B ----
    short* qkvb = (short*)(ws);              // 2048*2304*2 = 9437184
    short* hb   = (short*)(ws + 9437184);    // 2048*768*2  = 3145728 (hbuf/obuf)
    short* w1b  = (short*)(ws + 12582912);   // 3538944
    short* w2b  = (short*)(ws + 16121856);   // 1179648
    cvt_kernel<<<dim3(1024), dim3(256), 0, stream>>>(w1, w2, w1b, w2b);
    for (int b = 0; b < Bb; ++b) {
      const size_t ro = (size_t)b * Ll * Dd;
      ln_kernel<<<dim3(Ll), dim3(256), 0, stream>>>(x + ro, gamma, beta, hb);
      gemm_bt<0, 0><<<dim3(N1 / 128, Ll / 128), dim3(256), 0, stream>>>(
          hb, w1b, b1, nullptr, (void*)qkvb, N1, Dd);
      attn_kernel<<<dim3(Ll / 64, Hh), dim3(256), 0, stream>>>(qkvb, hb);
      gemm_bt<1, 0><<<dim3(Dd / 128, Ll / 128), dim3(256), 0, stream>>>(
          hb, w2b, b2, x + ro, (void*)(out + ro), Dd, Dd);
    }
  } else {
    // ---- T3: per-batch, fp32 weights staged on the fly.  ws = 12,582,912 B ----
    short* qkvb = (short*)(ws);              // 9437184
    short* hb   = (short*)(ws + 9437184);    // 3145728 (hbuf/obuf)
    for (int b = 0; b < Bb; ++b) {
      const size_t ro = (size_t)b * Ll * Dd;
      ln_kernel<<<dim3(Ll), dim3(256), 0, stream>>>(x + ro, gamma, beta, hb);
      gemm_bt<0, 1><<<dim3(N1 / 128, Ll / 128), dim3(256), 0, stream>>>(
          hb, w1, b1, nullptr, (void*)qkvb, N1, Dd);
      attn_kernel<<<dim3(Ll / 64, Hh), dim3(256), 0, stream>>>(qkvb, hb);
      gemm_bt<1, 1><<<dim3(Dd / 128, Ll / 128), dim3(256), 0, stream>>>(
          hb, w2, b2, x + ro, (void*)(out + ro), Dd, Dd);
    }
  }
}

// Round 9
// 127.898 us; speedup vs baseline: 1.2851x; 1.0615x over previous
//
#include <hip/hip_runtime.h>

// ---------------------------------------------------------------------------
// Fused pre-LN MHA block on MI355X (gfx950).
// B=2, L=2048, D=768, H=12, Dh=64.  All matmuls via mfma_f32_16x16x32_bf16.
// Pipeline: prep(LN+cvt) -> GEMM1 (qkv) -> flash-attn -> GEMM2+residual
// R8: counted-vmcnt pipelines (T3/T4): raw s_barrier + vmcnt(N) (never 0 in
// steady state) in attn AND double-buffered GEMM; s_setprio around attn MFMA.
// ---------------------------------------------------------------------------

#define DEV __device__ __forceinline__

typedef __attribute__((ext_vector_type(4))) float f32x4;
typedef __attribute__((ext_vector_type(8))) short s16x8;
typedef __attribute__((ext_vector_type(2))) int i32x2;

constexpr int Bb   = 2;
constexpr int Ll   = 2048;
constexpr int Dd   = 768;
constexpr int Hh   = 12;
constexpr int Dh   = 64;
constexpr int Mrows = Bb * Ll;      // 4096
constexpr int N1   = 3 * Dd;        // 2304

DEV unsigned short f2bf(float f) {
  union { float f; unsigned u; } v; v.f = f;
  unsigned r = v.u + 0x7fffu + ((v.u >> 16) & 1u);
  return (unsigned short)(r >> 16);
}

DEV void gload_lds16(const void* g, void* l) {
  __builtin_amdgcn_global_load_lds((const __attribute__((address_space(1))) unsigned int*)g,
                                   (__attribute__((address_space(3))) unsigned int*)l,
                                   16, 0, 0);
}

DEV f32x4 mfma16(s16x8 a, s16x8 b, f32x4 c) {
  return __builtin_amdgcn_mfma_f32_16x16x32_bf16(a, b, c, 0, 0, 0);
}

// reduce over lanes {l, l^16, l^32, l^48}: shfl for xor16, permlane32 for xor32
DEV float redmax64(float x) {
  x = fmaxf(x, __shfl_xor(x, 16, 64));
  float a = x, b = x;
  asm volatile("v_permlane32_swap_b32 %0, %1" : "+v"(a), "+v"(b));
  return fmaxf(a, b);
}
DEV float redsum64(float x) {
  x += __shfl_xor(x, 16, 64);
  float a = x, b = x;
  asm volatile("v_permlane32_swap_b32 %0, %1" : "+v"(a), "+v"(b));
  return a + b;
}

// ---------------------------------------------------------------------------
// LN body (one block per row, 256 thr) — used by prep_kernel and ln_kernel.
// ---------------------------------------------------------------------------
DEV void ln_body(int row, int t, const float* __restrict__ x,
                 const float* __restrict__ gamma, const float* __restrict__ beta,
                 short* __restrict__ hbuf, float* red) {
  const float* xr = x + (size_t)row * Dd;
  float v0 = xr[t], v1 = xr[t + 256], v2 = xr[t + 512];
  float s = v0 + v1 + v2;
  float q = v0 * v0 + v1 * v1 + v2 * v2;
#pragma unroll
  for (int off = 32; off; off >>= 1) {
    s += __shfl_xor(s, off, 64);
    q += __shfl_xor(q, off, 64);
  }
  const int w = t >> 6, lane = t & 63;
  if (lane == 0) { red[w] = s; red[4 + w] = q; }
  __syncthreads();
  s = red[0] + red[1] + red[2] + red[3];
  q = red[4] + red[5] + red[6] + red[7];
  const float mean = s * (1.f / Dd);
  const float var  = q * (1.f / Dd) - mean * mean;
  const float rstd = rsqrtf(var + 1e-5f);
  short* hr = hbuf + (size_t)row * Dd;
  hr[t]       = (short)f2bf((v0 - mean) * rstd * gamma[t]       + beta[t]);
  hr[t + 256] = (short)f2bf((v1 - mean) * rstd * gamma[t + 256] + beta[t + 256]);
  hr[t + 512] = (short)f2bf((v2 - mean) * rstd * gamma[t + 512] + beta[t + 512]);
}

constexpr int W1E = N1 * Dd;     // 1769472
constexpr int W2E = Dd * Dd;     // 589824

__global__ __launch_bounds__(256) void ln_kernel(const float* __restrict__ x,
                                                 const float* __restrict__ gamma,
                                                 const float* __restrict__ beta,
                                                 short* __restrict__ hbuf) {
  __shared__ float red[8];
  ln_body(blockIdx.x, threadIdx.x, x, gamma, beta, hbuf, red);
}

__global__ __launch_bounds__(256) void cvt_kernel(const float* __restrict__ w1,
                                                  const float* __restrict__ w2,
                                                  short* __restrict__ w1b,
                                                  short* __restrict__ w2b) {
  int i = blockIdx.x * 256 + threadIdx.x;
  const int stride = gridDim.x * 256;
  for (; i < W1E + W2E; i += stride) {
    if (i < W1E) w1b[i] = (short)f2bf(w1[i]);
    else         w2b[i - W1E] = (short)f2bf(w2[i - W1E]);
  }
}

// fused LN (blocks 0..Mrows-1) + weight cvt (blocks Mrows..Mrows+1023)
__global__ __launch_bounds__(256) void prep_kernel(const float* __restrict__ x,
                                                   const float* __restrict__ gamma,
                                                   const float* __restrict__ beta,
                                                   short* __restrict__ hbuf,
                                                   const float* __restrict__ w1,
                                                   const float* __restrict__ w2,
                                                   short* __restrict__ w1b,
                                                   short* __restrict__ w2b) {
  __shared__ float red[8];
  if (blockIdx.x < (unsigned)Mrows) {
    ln_body(blockIdx.x, threadIdx.x, x, gamma, beta, hbuf, red);
  } else {
    int i = (blockIdx.x - Mrows) * 256 + threadIdx.x;
    for (; i < W1E + W2E; i += 1024 * 256) {
      if (i < W1E) w1b[i] = (short)f2bf(w1[i]);
      else         w2b[i - W1E] = (short)f2bf(w2[i - W1E]);
    }
  }
}

// ---------------------------------------------------------------------------
// GEMM (B^T form): C[m][n] = sum_k A[m][k] * W[n][k] (+bias)(+resid)
// 128x128 tile, BK=64, 4 waves (2x2), each wave 64x64 = 4x4 16x16 frags.
// WSRC 0: double-buffered LDS + counted-vmcnt pipeline (raw barriers):
//   prologue stages tiles 0,1; per iter: vmcnt(8) [wait own tile loads,
//   leave next tile's 8 in flight] -> bar -> MFMA -> bar -> stage tile+2.
// WSRC 1 (fp32 weights, T3 tier): old single-buffer __syncthreads loop.
// LDS tiles XOR-swizzled via pre-swizzled global source (m173 pattern).
// ---------------------------------------------------------------------------
template <int EPI, int WSRC>
__global__ __launch_bounds__(256) void gemm_bt(const short* __restrict__ A,
                                               const void* __restrict__ Wp,
                                               const float* __restrict__ bias,
                                               const float* __restrict__ resid,
                                               void* __restrict__ outp,
                                               int N, int K) {
  __shared__ __align__(16) short As[2][128 * 64];
  __shared__ __align__(16) short Ws[2][128 * 64];
  const int tid  = threadIdx.x;
  const int lane = tid & 63, wid = tid >> 6;
  const int wr = wid >> 1, wc = wid & 1;
  const int g = lane >> 4, li = lane & 15;
  const int brow = blockIdx.y * 128, bcol = blockIdx.x * 128;

  f32x4 acc[4][4];
#pragma unroll
  for (int m = 0; m < 4; ++m)
#pragma unroll
    for (int n = 0; n < 4; ++n)
#pragma unroll
      for (int r = 0; r < 4; ++r) acc[m][n][r] = 0.f;

  if constexpr (WSRC == 0) {
    const short* W = (const short*)Wp;
    const int nt = K >> 6;
    auto stage = [&](int t, int buf) {
      const int ko = t << 6;
#pragma unroll
      for (int i = 0; i < 4; ++i) {
        const int idx = i * 256 + tid;
        const int r = idx >> 3, c = idx & 7;
        const int cs = c ^ (r & 7);
        gload_lds16(A + (size_t)(brow + r) * K + ko + cs * 8,
                    (char*)&As[buf][0] + idx * 16);
        gload_lds16(W + (size_t)(bcol + r) * K + ko + cs * 8,
                    (char*)&Ws[buf][0] + idx * 16);
      }
    };
    stage(0, 0);
    stage(1, 1);
    for (int it = 0; it < nt; ++it) {
      const int cur = it & 1;
      if (it + 1 < nt) asm volatile("s_waitcnt vmcnt(8)" ::: "memory");
      else             asm volatile("s_waitcnt vmcnt(0)" ::: "memory");
      __builtin_amdgcn_s_barrier();
      __builtin_amdgcn_sched_barrier(0);
#pragma unroll
      for (int kk = 0; kk < 2; ++kk) {
        s16x8 af[4], bf[4];
#pragma unroll
        for (int m = 0; m < 4; ++m) {
          const int row = wr * 64 + m * 16 + li;
          af[m] = *(const s16x8*)&As[cur][row * 64 + (((kk * 4 + g) ^ (li & 7)) & 7) * 8];
        }
#pragma unroll
        for (int n = 0; n < 4; ++n) {
          const int row = wc * 64 + n * 16 + li;
          bf[n] = *(const s16x8*)&Ws[cur][row * 64 + (((kk * 4 + g) ^ (li & 7)) & 7) * 8];
        }
#pragma unroll
        for (int m = 0; m < 4; ++m)
#pragma unroll
          for (int n = 0; n < 4; ++n)
            acc[m][n] = mfma16(af[m], bf[n], acc[m][n]);
      }
      __builtin_amdgcn_s_barrier();
      if (it + 2 < nt) stage(it + 2, cur);
    }
  } else {
    const float* W = (const float*)Wp;
    for (int kt = 0; kt < K; kt += 64) {
#pragma unroll
      for (int i = 0; i < 4; ++i) {
        const int idx = i * 256 + tid;
        const int r = idx >> 3, c = idx & 7;
        const int cs = c ^ (r & 7);
        gload_lds16(A + (size_t)(brow + r) * K + kt + cs * 8,
                    (char*)&As[0][0] + idx * 16);
      }
#pragma unroll
      for (int i = 0; i < 4; ++i) {
        const int idx = i * 256 + tid;
        const int r = idx >> 3, c = idx & 7;
        const float* wp = W + (size_t)(bcol + r) * K + kt + c * 8;
        const f32x4 lo = *(const f32x4*)wp;
        const f32x4 hi = *(const f32x4*)(wp + 4);
        s16x8 o;
#pragma unroll
        for (int j = 0; j < 4; ++j) {
          o[j]     = (short)f2bf(lo[j]);
          o[4 + j] = (short)f2bf(hi[j]);
        }
        *(s16x8*)((char*)&Ws[0][0] + (size_t)(r * 8 + (c ^ (r & 7))) * 16) = o;
      }
      __syncthreads();
#pragma unroll
      for (int kk = 0; kk < 2; ++kk) {
        s16x8 af[4], bf[4];
#pragma unroll
        for (int m = 0; m < 4; ++m) {
          const int row = wr * 64 + m * 16 + li;
          af[m] = *(const s16x8*)&As[0][row * 64 + (((kk * 4 + g) ^ (li & 7)) & 7) * 8];
        }
#pragma unroll
        for (int n = 0; n < 4; ++n) {
          const int row = wc * 64 + n * 16 + li;
          bf[n] = *(const s16x8*)&Ws[0][row * 64 + (((kk * 4 + g) ^ (li & 7)) & 7) * 8];
        }
#pragma unroll
        for (int m = 0; m < 4; ++m)
#pragma unroll
          for (int n = 0; n < 4; ++n)
            acc[m][n] = mfma16(af[m], bf[n], acc[m][n]);
      }
      __syncthreads();
    }
  }

#pragma unroll
  for (int m = 0; m < 4; ++m) {
#pragma unroll
    for (int n = 0; n < 4; ++n) {
      const int col = bcol + wc * 64 + n * 16 + li;
      const float bv = bias[col];
#pragma unroll
      for (int r = 0; r < 4; ++r) {
        const int row = brow + wr * 64 + m * 16 + g * 4 + r;
        const float v = acc[m][n][r] + bv;
        if (EPI == 0) {
          ((short*)outp)[(size_t)row * N + col] = (short)f2bf(v);
        } else {
          const size_t o = (size_t)row * N + col;
          ((float*)outp)[o] = v + resid[o];
        }
      }
    }
  }
}

// ---------------------------------------------------------------------------
// Flash attention R8 (= R7 + counted-vmcnt pipeline + setprio).
// Grid (L/64, nbatch*H), 256 thr = 4 waves; wave owns 16 q rows.  KVBLK=64,
// double-buffered K (XOR-swizzled) + V (tr-subtiled) via global_load_lds.
// Pipeline: prologue stages tiles 0,1; per iter: vmcnt(4) [wait current
// tile's 4 loads, leave next tile's in flight] -> bar -> compute -> bar ->
// stage tile+2.  Raw barriers, no vmcnt(0) drains in steady state.
// ---------------------------------------------------------------------------
#define TRRD(dst, addr, OFF)                                                   \
  asm volatile("ds_read_b64_tr_b16 %0, %1 offset:" #OFF                        \
               : "=v"(dst) : "v"(addr))

__global__ __launch_bounds__(256) void attn_kernel(const short* __restrict__ qkv,
                                                   short* __restrict__ obuf) {
  __shared__ __align__(16) short Ks[2][64 * 64];
  __shared__ __align__(16) short Vt[2][64 * 64];
  __shared__ __align__(16) short Ps[4][16 * 64];
  const int tid  = threadIdx.x;
  const int lane = tid & 63, w = tid >> 6;
  const int g = lane >> 4, li = lane & 15;
  const int bh = blockIdx.y;
  const int b = bh / Hh, h = bh % Hh;
  const size_t rowbase = (size_t)b * Ll * N1;
  const int q0 = blockIdx.x * 64 + w * 16;
  constexpr float kScale = 0.125f * 1.44269504f;   // 1/sqrt(Dh) * log2(e)
  constexpr float kThrRaw = 8.f / kScale;          // defer-max threshold (raw)
  constexpr int KVSTRIDE = 64 * N1;                // elements per KV tile

  // Q fragments (B operand of swapped QK^T)
  s16x8 qf[2];
#pragma unroll
  for (int ks = 0; ks < 2; ++ks)
    qf[ks] = *(const s16x8*)(qkv + rowbase + (size_t)(q0 + li) * N1 +
                             h * Dh + ks * 32 + g * 8);

  f32x4 oa[4];
  float m_ = -1e30f, l_ = 0.f;   // per-lane: q = li ; m_ in RAW domain
#pragma unroll
  for (int dn = 0; dn < 4; ++dn)
#pragma unroll
    for (int r = 0; r < 4; ++r) oa[dn][r] = 0.f;

  constexpr int NT = Ll / 64;  // 32 tiles

  // ---- hoisted staging source pointers (advance by KVSTRIDE per stage) ----
  const int ia = tid, ib = 256 + tid;
  const int ra = ia >> 3, ca = ia & 7, rb = ib >> 3, cb = ib & 7;
  const short* kpa = qkv + rowbase + Dd + h * Dh + (size_t)ra * N1 + (ca ^ (ra & 7)) * 8;
  const short* kpb = qkv + rowbase + Dd + h * Dh + (size_t)rb * N1 + (cb ^ (rb & 7)) * 8;
  const int Ta = ia >> 3, Tb = ib >> 3;
  const short* vpa = qkv + rowbase + 2 * Dd + h * Dh +
                     (size_t)((Ta & 15) * 4 + (ca >> 1)) * N1 + (Ta >> 4) * 16 + (ia & 1) * 8;
  const short* vpb = qkv + rowbase + 2 * Dd + h * Dh +
                     (size_t)((Tb & 15) * 4 + (cb >> 1)) * N1 + (Tb >> 4) * 16 + (ib & 1) * 8;
  char* KsB = (char*)&Ks[0][0];
  char* VtB = (char*)&Vt[0][0];
  const int dsta = ia * 16, dstb = ib * 16;

  // ---- hoisted LDS fragment offsets (bytes) ----
  int koff[4][2];
#pragma unroll
  for (int n = 0; n < 4; ++n) {
    koff[n][0] = ((n * 16 + li) * 64 + ((g ^ (li & 7)) & 7) * 8) * 2;
    koff[n][1] = ((n * 16 + li) * 64 + (((4 + g) ^ (li & 7)) & 7) * 8) * 2;
  }
  int pwoff[4], proff[2];
#pragma unroll
  for (int n = 0; n < 4; ++n)
    pwoff[n] = li * 128 + (((2 * n + (g >> 1)) ^ (li & 7)) << 4) + 8 * (g & 1);
#pragma unroll
  for (int kk = 0; kk < 2; ++kk)
    proff[kk] = li * 128 + (((4 * kk + g) ^ (li & 7)) << 4);
  char* Pw = (char*)&Ps[w][0];
  const unsigned vlane = (unsigned)((lane >> 4) * 256 + (lane & 15) * 2);
  const unsigned vbase0 = (unsigned)(unsigned long long)(&Vt[0][0]) + vlane;

  auto stage = [&](int buf) {
    const int bo = buf << 13;
    gload_lds16(kpa, KsB + bo + dsta);
    gload_lds16(kpb, KsB + bo + dstb);
    gload_lds16(vpa, VtB + bo + dsta);
    gload_lds16(vpb, VtB + bo + dstb);
    kpa += KVSTRIDE; kpb += KVSTRIDE; vpa += KVSTRIDE; vpb += KVSTRIDE;
  };

  stage(0);   // tile 0 -> buf 0
  stage(1);   // tile 1 -> buf 1   (8 loads in flight)

  for (int kt = 0; kt < NT; ++kt) {
    const int cur = kt & 1;
    const int curo = cur << 13;
    if (kt + 1 < NT) asm volatile("s_waitcnt vmcnt(4)" ::: "memory");
    else             asm volatile("s_waitcnt vmcnt(0)" ::: "memory");
    __builtin_amdgcn_s_barrier();
    __builtin_amdgcn_sched_barrier(0);

    // ---- Z^T = mfma(K, Q)  (raw dot products) ----
    f32x4 s[4];
    __builtin_amdgcn_s_setprio(1);
#pragma unroll
    for (int n = 0; n < 4; ++n) {
      s16x8 kf0 = *(const s16x8*)(KsB + curo + koff[n][0]);
      s16x8 kf1 = *(const s16x8*)(KsB + curo + koff[n][1]);
      f32x4 z;
#pragma unroll
      for (int r = 0; r < 4; ++r) z[r] = 0.f;
      z = mfma16(kf0, qf[0], z);
      z = mfma16(kf1, qf[1], z);
      s[n] = z;
    }
    __builtin_amdgcn_s_setprio(0);

    // ---- online softmax, raw-domain max, per-lane q = li ----
    const float l0 = fmaxf(fmaxf(s[0][0], s[0][1]), s[0][2]);
    const float l1 = fmaxf(fmaxf(s[0][3], s[1][0]), s[1][1]);
    const float l2 = fmaxf(fmaxf(s[1][2], s[1][3]), s[2][0]);
    const float l3 = fmaxf(fmaxf(s[2][1], s[2][2]), s[2][3]);
    const float l4 = fmaxf(fmaxf(s[3][0], s[3][1]), s[3][2]);
    float mx = fmaxf(fmaxf(fmaxf(fmaxf(l0, l1), l2), fmaxf(l3, l4)), s[3][3]);
    mx = redmax64(mx);
    if (!__all(mx - m_ <= kThrRaw)) {
      const float mnew = fmaxf(m_, mx);
      const float sc = exp2f((m_ - mnew) * kScale);
      float scq[4];
#pragma unroll
      for (int r = 0; r < 4; ++r)
        scq[r] = __shfl(sc, (lane & 48) + ((lane & 48) >> 2) + r, 64);
#pragma unroll
      for (int dn = 0; dn < 4; ++dn)
#pragma unroll
        for (int r = 0; r < 4; ++r) oa[dn][r] *= scq[r];
      l_ *= sc;
      m_ = mnew;
    }
    const float msc = m_ * kScale;
    float rs = 0.f;
#pragma unroll
    for (int n = 0; n < 4; ++n)
#pragma unroll
      for (int r = 0; r < 4; ++r) {
        const float p = exp2f(fmaf(s[n][r], kScale, -msc));
        s[n][r] = p;
        rs += p;
      }
    rs = redsum64(rs);
    l_ += rs;

    // ---- P pack via cvt_pk -> swizzled per-wave LDS (4 x ds_write_b64) ----
#pragma unroll
    for (int n = 0; n < 4; ++n) {
      unsigned u0, u1;
      asm("v_cvt_pk_bf16_f32 %0, %1, %2" : "=v"(u0) : "v"(s[n][0]), "v"(s[n][1]));
      asm("v_cvt_pk_bf16_f32 %0, %1, %2" : "=v"(u1) : "v"(s[n][2]), "v"(s[n][3]));
      i32x2 pv; pv[0] = (int)u0; pv[1] = (int)u1;
      *(i32x2*)(Pw + pwoff[n]) = pv;
    }

    // ---- P A-frag reads (2 x b128) ----
    s16x8 pf[2];
#pragma unroll
    for (int kk = 0; kk < 2; ++kk)
      pf[kk] = *(const s16x8*)(Pw + proff[kk]);

    // ---- V^T fragments via HW transpose reads (16 x ds_read_b64_tr_b16) ----
    union VU { long l[2]; s16x8 v; };
    VU vu[4][2];
    {
      const unsigned vaddr = vbase0 + (unsigned)curo;
      TRRD(vu[0][0].l[0], vaddr, 0);    TRRD(vu[0][0].l[1], vaddr, 128);
      TRRD(vu[0][1].l[0], vaddr, 1024); TRRD(vu[0][1].l[1], vaddr, 1152);
      TRRD(vu[1][0].l[0], vaddr, 2048); TRRD(vu[1][0].l[1], vaddr, 2176);
      TRRD(vu[1][1].l[0], vaddr, 3072); TRRD(vu[1][1].l[1], vaddr, 3200);
      TRRD(vu[2][0].l[0], vaddr, 4096); TRRD(vu[2][0].l[1], vaddr, 4224);
      TRRD(vu[2][1].l[0], vaddr, 5120); TRRD(vu[2][1].l[1], vaddr, 5248);
      TRRD(vu[3][0].l[0], vaddr, 6144); TRRD(vu[3][0].l[1], vaddr, 6272);
      TRRD(vu[3][1].l[0], vaddr, 7168); TRRD(vu[3][1].l[1], vaddr, 7296);
    }
    asm volatile("s_waitcnt lgkmcnt(0)" ::: "memory");
    __builtin_amdgcn_sched_barrier(0);

    // ---- O += P V ----
    __builtin_amdgcn_s_setprio(1);
#pragma unroll
    for (int dn = 0; dn < 4; ++dn) {
      oa[dn] = mfma16(pf[0], vu[dn][0].v, oa[dn]);
      oa[dn] = mfma16(pf[1], vu[dn][1].v, oa[dn]);
    }
    __builtin_amdgcn_s_setprio(0);

    __builtin_amdgcn_s_barrier();
    if (kt + 2 < NT) stage(cur);   // tile kt+2 -> buf cur
  }

  // ---- O / l -> bf16 obuf (row q = q0 + g*4 + r) ----
  {
#pragma unroll
    for (int r = 0; r < 4; ++r) {
      const float lq = __shfl(l_, (lane & 48) + ((lane & 48) >> 2) + r, 64);
      const float inv = 1.f / lq;
      const int row = b * Ll + q0 + g * 4 + r;
#pragma unroll
      for (int dn = 0; dn < 4; ++dn)
        obuf[(size_t)row * Dd + h * Dh + dn * 16 + li] =
            (short)f2bf(oa[dn][r] * inv);
    }
  }
}

// ---------------------------------------------------------------------------
extern "C" void kernel_launch(void* const* d_in, const int* in_sizes, int n_in,
                              void* d_out, int out_size, void* d_ws, size_t ws_size,
                              hipStream_t stream) {
  const float* x     = (const float*)d_in[0];
  const float* gamma = (const float*)d_in[1];
  const float* beta  = (const float*)d_in[2];
  const float* w1    = (const float*)d_in[3];
  const float* b1    = (const float*)d_in[4];
  const float* w2    = (const float*)d_in[5];
  const float* b2    = (const float*)d_in[6];
  float* out = (float*)d_out;
  char* ws = (char*)d_ws;

  if (ws_size >= 29884416) {
    // ---- T1: full batch in one pass.  ws = 29,884,416 B ----
    short* qkvb = (short*)(ws);              // 4096*2304*2 = 18874368
    short* hb   = (short*)(ws + 18874368);   // 4096*768*2  = 6291456 (hbuf, then obuf)
    short* w1b  = (short*)(ws + 25165824);   // 2304*768*2  = 3538944
    short* w2b  = (short*)(ws + 28704768);   // 768*768*2   = 1179648
    prep_kernel<<<dim3(Mrows + 1024), dim3(256), 0, stream>>>(
        x, gamma, beta, hb, w1, w2, w1b, w2b);
    gemm_bt<0, 0><<<dim3(N1 / 128, Mrows / 128), dim3(256), 0, stream>>>(
        hb, w1b, b1, nullptr, (void*)qkvb, N1, Dd);
    attn_kernel<<<dim3(Ll / 64, Bb * Hh), dim3(256), 0, stream>>>(qkvb, hb);
    gemm_bt<1, 0><<<dim3(Dd / 128, Mrows / 128), dim3(256), 0, stream>>>(
        hb, w2b, b2, x, (void*)out, Dd, Dd);
  } else if (ws_size >= 17301504) {
    // ---- T2: per-batch, bf16 weights.  ws = 17,301,504 B ----
    short* qkvb = (short*)(ws);              // 2048*2304*2 = 9437184
    short* hb   = (short*)(ws + 9437184);    // 2048*768*2  = 3145728 (hbuf/obuf)
    short* w1b  = (short*)(ws + 12582912);   // 3538944
    short* w2b  = (short*)(ws + 16121856);   // 1179648
    cvt_kernel<<<dim3(1024), dim3(256), 0, stream>>>(w1, w2, w1b, w2b);
    for (int b = 0; b < Bb; ++b) {
      const size_t ro = (size_t)b * Ll * Dd;
      ln_kernel<<<dim3(Ll), dim3(256), 0, stream>>>(x + ro, gamma, beta, hb);
      gemm_bt<0, 0><<<dim3(N1 / 128, Ll / 128), dim3(256), 0, stream>>>(
          hb, w1b, b1, nullptr, (void*)qkvb, N1, Dd);
      attn_kernel<<<dim3(Ll / 64, Hh), dim3(256), 0, stream>>>(qkvb, hb);
      gemm_bt<1, 0><<<dim3(Dd / 128, Ll / 128), dim3(256), 0, stream>>>(
          hb, w2b, b2, x + ro, (void*)(out + ro), Dd, Dd);
    }
  } else {
    // ---- T3: per-batch, fp32 weights staged on the fly.  ws = 12,582,912 B ----
    short* qkvb = (short*)(ws);              // 9437184
    short* hb   = (short*)(ws + 9437184);    // 3145728 (hbuf/obuf)
    for (int b = 0; b < Bb; ++b) {
      const size_t ro = (size_t)b * Ll * Dd;
      ln_kernel<<<dim3(Ll), dim3(256), 0, stream>>>(x + ro, gamma, beta, hb);
      gemm_bt<0, 1><<<dim3(N1 / 128, Ll / 128), dim3(256), 0, stream>>>(
          hb, w1, b1, nullptr, (void*)qkvb, N1, Dd);
      attn_kernel<<<dim3(Ll / 64, Hh), dim3(256), 0, stream>>>(qkvb, hb);
      gemm_bt<1, 1><<<dim3(Dd / 128, Ll / 128), dim3(256), 0, stream>>>(
          hb, w2, b2, x + ro, (void*)(out + ro), Dd, Dd);
    }
  }
}

// Round 10
// 116.374 us; speedup vs baseline: 1.4123x; 1.0990x over previous
//
#include <hip/hip_runtime.h>

// ---------------------------------------------------------------------------
// Fused pre-LN MHA block on MI355X (gfx950).
// B=2, L=2048, D=768, H=12, Dh=64.  All matmuls via mfma_f32_16x16x32_bf16.
// Pipeline: prep(LN+cvt) -> GEMM1 (qkv) -> flash-attn -> GEMM2+residual
// R9: exp2f was compiling to the multi-instruction ocml path (no fast-math);
// replaced with raw v_exp_f32 (which IS 2^x) + v_rcp_f32 for the epilogue
// divides.  Rest identical to the R8 pipeline (counted vmcnt, dbuf GEMM).
// ---------------------------------------------------------------------------

#define DEV __device__ __forceinline__

typedef __attribute__((ext_vector_type(4))) float f32x4;
typedef __attribute__((ext_vector_type(8))) short s16x8;
typedef __attribute__((ext_vector_type(2))) int i32x2;

constexpr int Bb   = 2;
constexpr int Ll   = 2048;
constexpr int Dd   = 768;
constexpr int Hh   = 12;
constexpr int Dh   = 64;
constexpr int Mrows = Bb * Ll;      // 4096
constexpr int N1   = 3 * Dd;        // 2304

DEV unsigned short f2bf(float f) {
  union { float f; unsigned u; } v; v.f = f;
  unsigned r = v.u + 0x7fffu + ((v.u >> 16) & 1u);
  return (unsigned short)(r >> 16);
}

DEV void gload_lds16(const void* g, void* l) {
  __builtin_amdgcn_global_load_lds((const __attribute__((address_space(1))) unsigned int*)g,
                                   (__attribute__((address_space(3))) unsigned int*)l,
                                   16, 0, 0);
}

DEV f32x4 mfma16(s16x8 a, s16x8 b, f32x4 c) {
  return __builtin_amdgcn_mfma_f32_16x16x32_bf16(a, b, c, 0, 0, 0);
}

// single-instruction 2^x and 1/x (ocml paths are 10+ instrs without fast-math)
DEV float fexp2(float x) { float r; asm("v_exp_f32 %0, %1" : "=v"(r) : "v"(x)); return r; }
DEV float frcp(float x)  { float r; asm("v_rcp_f32 %0, %1" : "=v"(r) : "v"(x)); return r; }

// reduce over lanes {l, l^16, l^32, l^48}: shfl for xor16, permlane32 for xor32
DEV float redmax64(float x) {
  x = fmaxf(x, __shfl_xor(x, 16, 64));
  float a = x, b = x;
  asm volatile("v_permlane32_swap_b32 %0, %1" : "+v"(a), "+v"(b));
  return fmaxf(a, b);
}
DEV float redsum64(float x) {
  x += __shfl_xor(x, 16, 64);
  float a = x, b = x;
  asm volatile("v_permlane32_swap_b32 %0, %1" : "+v"(a), "+v"(b));
  return a + b;
}

// ---------------------------------------------------------------------------
// LN body (one block per row, 256 thr) — used by prep_kernel and ln_kernel.
// ---------------------------------------------------------------------------
DEV void ln_body(int row, int t, const float* __restrict__ x,
                 const float* __restrict__ gamma, const float* __restrict__ beta,
                 short* __restrict__ hbuf, float* red) {
  const float* xr = x + (size_t)row * Dd;
  float v0 = xr[t], v1 = xr[t + 256], v2 = xr[t + 512];
  float s = v0 + v1 + v2;
  float q = v0 * v0 + v1 * v1 + v2 * v2;
#pragma unroll
  for (int off = 32; off; off >>= 1) {
    s += __shfl_xor(s, off, 64);
    q += __shfl_xor(q, off, 64);
  }
  const int w = t >> 6, lane = t & 63;
  if (lane == 0) { red[w] = s; red[4 + w] = q; }
  __syncthreads();
  s = red[0] + red[1] + red[2] + red[3];
  q = red[4] + red[5] + red[6] + red[7];
  const float mean = s * (1.f / Dd);
  const float var  = q * (1.f / Dd) - mean * mean;
  const float rstd = rsqrtf(var + 1e-5f);
  short* hr = hbuf + (size_t)row * Dd;
  hr[t]       = (short)f2bf((v0 - mean) * rstd * gamma[t]       + beta[t]);
  hr[t + 256] = (short)f2bf((v1 - mean) * rstd * gamma[t + 256] + beta[t + 256]);
  hr[t + 512] = (short)f2bf((v2 - mean) * rstd * gamma[t + 512] + beta[t + 512]);
}

constexpr int W1E = N1 * Dd;     // 1769472
constexpr int W2E = Dd * Dd;     // 589824

__global__ __launch_bounds__(256) void ln_kernel(const float* __restrict__ x,
                                                 const float* __restrict__ gamma,
                                                 const float* __restrict__ beta,
                                                 short* __restrict__ hbuf) {
  __shared__ float red[8];
  ln_body(blockIdx.x, threadIdx.x, x, gamma, beta, hbuf, red);
}

__global__ __launch_bounds__(256) void cvt_kernel(const float* __restrict__ w1,
                                                  const float* __restrict__ w2,
                                                  short* __restrict__ w1b,
                                                  short* __restrict__ w2b) {
  int i = blockIdx.x * 256 + threadIdx.x;
  const int stride = gridDim.x * 256;
  for (; i < W1E + W2E; i += stride) {
    if (i < W1E) w1b[i] = (short)f2bf(w1[i]);
    else         w2b[i - W1E] = (short)f2bf(w2[i - W1E]);
  }
}

// fused LN (blocks 0..Mrows-1) + weight cvt (blocks Mrows..Mrows+1023)
__global__ __launch_bounds__(256) void prep_kernel(const float* __restrict__ x,
                                                   const float* __restrict__ gamma,
                                                   const float* __restrict__ beta,
                                                   short* __restrict__ hbuf,
                                                   const float* __restrict__ w1,
                                                   const float* __restrict__ w2,
                                                   short* __restrict__ w1b,
                                                   short* __restrict__ w2b) {
  __shared__ float red[8];
  if (blockIdx.x < (unsigned)Mrows) {
    ln_body(blockIdx.x, threadIdx.x, x, gamma, beta, hbuf, red);
  } else {
    int i = (blockIdx.x - Mrows) * 256 + threadIdx.x;
    for (; i < W1E + W2E; i += 1024 * 256) {
      if (i < W1E) w1b[i] = (short)f2bf(w1[i]);
      else         w2b[i - W1E] = (short)f2bf(w2[i - W1E]);
    }
  }
}

// ---------------------------------------------------------------------------
// GEMM (B^T form): C[m][n] = sum_k A[m][k] * W[n][k] (+bias)(+resid)
// 128x128 tile, BK=64, 4 waves (2x2), each wave 64x64 = 4x4 16x16 frags.
// WSRC 0: double-buffered LDS + counted-vmcnt pipeline (raw barriers).
// WSRC 1 (fp32 weights, T3 tier): old single-buffer __syncthreads loop.
// LDS tiles XOR-swizzled via pre-swizzled global source (m173 pattern).
// ---------------------------------------------------------------------------
template <int EPI, int WSRC>
__global__ __launch_bounds__(256) void gemm_bt(const short* __restrict__ A,
                                               const void* __restrict__ Wp,
                                               const float* __restrict__ bias,
                                               const float* __restrict__ resid,
                                               void* __restrict__ outp,
                                               int N, int K) {
  __shared__ __align__(16) short As[2][128 * 64];
  __shared__ __align__(16) short Ws[2][128 * 64];
  const int tid  = threadIdx.x;
  const int lane = tid & 63, wid = tid >> 6;
  const int wr = wid >> 1, wc = wid & 1;
  const int g = lane >> 4, li = lane & 15;
  const int brow = blockIdx.y * 128, bcol = blockIdx.x * 128;

  f32x4 acc[4][4];
#pragma unroll
  for (int m = 0; m < 4; ++m)
#pragma unroll
    for (int n = 0; n < 4; ++n)
#pragma unroll
      for (int r = 0; r < 4; ++r) acc[m][n][r] = 0.f;

  if constexpr (WSRC == 0) {
    const short* W = (const short*)Wp;
    const int nt = K >> 6;
    auto stage = [&](int t, int buf) {
      const int ko = t << 6;
#pragma unroll
      for (int i = 0; i < 4; ++i) {
        const int idx = i * 256 + tid;
        const int r = idx >> 3, c = idx & 7;
        const int cs = c ^ (r & 7);
        gload_lds16(A + (size_t)(brow + r) * K + ko + cs * 8,
                    (char*)&As[buf][0] + idx * 16);
        gload_lds16(W + (size_t)(bcol + r) * K + ko + cs * 8,
                    (char*)&Ws[buf][0] + idx * 16);
      }
    };
    stage(0, 0);
    stage(1, 1);
    for (int it = 0; it < nt; ++it) {
      const int cur = it & 1;
      if (it + 1 < nt) asm volatile("s_waitcnt vmcnt(8)" ::: "memory");
      else             asm volatile("s_waitcnt vmcnt(0)" ::: "memory");
      __builtin_amdgcn_s_barrier();
      __builtin_amdgcn_sched_barrier(0);
#pragma unroll
      for (int kk = 0; kk < 2; ++kk) {
        s16x8 af[4], bf[4];
#pragma unroll
        for (int m = 0; m < 4; ++m) {
          const int row = wr * 64 + m * 16 + li;
          af[m] = *(const s16x8*)&As[cur][row * 64 + (((kk * 4 + g) ^ (li & 7)) & 7) * 8];
        }
#pragma unroll
        for (int n = 0; n < 4; ++n) {
          const int row = wc * 64 + n * 16 + li;
          bf[n] = *(const s16x8*)&Ws[cur][row * 64 + (((kk * 4 + g) ^ (li & 7)) & 7) * 8];
        }
#pragma unroll
        for (int m = 0; m < 4; ++m)
#pragma unroll
          for (int n = 0; n < 4; ++n)
            acc[m][n] = mfma16(af[m], bf[n], acc[m][n]);
      }
      __builtin_amdgcn_s_barrier();
      if (it + 2 < nt) stage(it + 2, cur);
    }
  } else {
    const float* W = (const float*)Wp;
    for (int kt = 0; kt < K; kt += 64) {
#pragma unroll
      for (int i = 0; i < 4; ++i) {
        const int idx = i * 256 + tid;
        const int r = idx >> 3, c = idx & 7;
        const int cs = c ^ (r & 7);
        gload_lds16(A + (size_t)(brow + r) * K + kt + cs * 8,
                    (char*)&As[0][0] + idx * 16);
      }
#pragma unroll
      for (int i = 0; i < 4; ++i) {
        const int idx = i * 256 + tid;
        const int r = idx >> 3, c = idx & 7;
        const float* wp = W + (size_t)(bcol + r) * K + kt + c * 8;
        const f32x4 lo = *(const f32x4*)wp;
        const f32x4 hi = *(const f32x4*)(wp + 4);
        s16x8 o;
#pragma unroll
        for (int j = 0; j < 4; ++j) {
          o[j]     = (short)f2bf(lo[j]);
          o[4 + j] = (short)f2bf(hi[j]);
        }
        *(s16x8*)((char*)&Ws[0][0] + (size_t)(r * 8 + (c ^ (r & 7))) * 16) = o;
      }
      __syncthreads();
#pragma unroll
      for (int kk = 0; kk < 2; ++kk) {
        s16x8 af[4], bf[4];
#pragma unroll
        for (int m = 0; m < 4; ++m) {
          const int row = wr * 64 + m * 16 + li;
          af[m] = *(const s16x8*)&As[0][row * 64 + (((kk * 4 + g) ^ (li & 7)) & 7) * 8];
        }
#pragma unroll
        for (int n = 0; n < 4; ++n) {
          const int row = wc * 64 + n * 16 + li;
          bf[n] = *(const s16x8*)&Ws[0][row * 64 + (((kk * 4 + g) ^ (li & 7)) & 7) * 8];
        }
#pragma unroll
        for (int m = 0; m < 4; ++m)
#pragma unroll
          for (int n = 0; n < 4; ++n)
            acc[m][n] = mfma16(af[m], bf[n], acc[m][n]);
      }
      __syncthreads();
    }
  }

#pragma unroll
  for (int m = 0; m < 4; ++m) {
#pragma unroll
    for (int n = 0; n < 4; ++n) {
      const int col = bcol + wc * 64 + n * 16 + li;
      const float bv = bias[col];
#pragma unroll
      for (int r = 0; r < 4; ++r) {
        const int row = brow + wr * 64 + m * 16 + g * 4 + r;
        const float v = acc[m][n][r] + bv;
        if (EPI == 0) {
          ((short*)outp)[(size_t)row * N + col] = (short)f2bf(v);
        } else {
          const size_t o = (size_t)row * N + col;
          ((float*)outp)[o] = v + resid[o];
        }
      }
    }
  }
}

// ---------------------------------------------------------------------------
// Flash attention R9 (= R8 + raw v_exp_f32 / v_rcp_f32).
// Grid (L/64, nbatch*H), 256 thr = 4 waves; wave owns 16 q rows.  KVBLK=64,
// double-buffered K (XOR-swizzled) + V (tr-subtiled) via global_load_lds.
// Pipeline: prologue stages tiles 0,1; per iter: vmcnt(4) -> bar -> compute
// -> bar -> stage tile+2.  Raw barriers, counted vmcnt (0 only at last tile).
// ---------------------------------------------------------------------------
#define TRRD(dst, addr, OFF)                                                   \
  asm volatile("ds_read_b64_tr_b16 %0, %1 offset:" #OFF                        \
               : "=v"(dst) : "v"(addr))

__global__ __launch_bounds__(256) void attn_kernel(const short* __restrict__ qkv,
                                                   short* __restrict__ obuf) {
  __shared__ __align__(16) short Ks[2][64 * 64];
  __shared__ __align__(16) short Vt[2][64 * 64];
  __shared__ __align__(16) short Ps[4][16 * 64];
  const int tid  = threadIdx.x;
  const int lane = tid & 63, w = tid >> 6;
  const int g = lane >> 4, li = lane & 15;
  const int bh = blockIdx.y;
  const int b = bh / Hh, h = bh % Hh;
  const size_t rowbase = (size_t)b * Ll * N1;
  const int q0 = blockIdx.x * 64 + w * 16;
  constexpr float kScale = 0.125f * 1.44269504f;   // 1/sqrt(Dh) * log2(e)
  constexpr float kThrRaw = 8.f / kScale;          // defer-max threshold (raw)
  constexpr int KVSTRIDE = 64 * N1;                // elements per KV tile

  // Q fragments (B operand of swapped QK^T)
  s16x8 qf[2];
#pragma unroll
  for (int ks = 0; ks < 2; ++ks)
    qf[ks] = *(const s16x8*)(qkv + rowbase + (size_t)(q0 + li) * N1 +
                             h * Dh + ks * 32 + g * 8);

  f32x4 oa[4];
  float m_ = -1e30f, l_ = 0.f;   // per-lane: q = li ; m_ in RAW domain
#pragma unroll
  for (int dn = 0; dn < 4; ++dn)
#pragma unroll
    for (int r = 0; r < 4; ++r) oa[dn][r] = 0.f;

  constexpr int NT = Ll / 64;  // 32 tiles

  // ---- hoisted staging source pointers (advance by KVSTRIDE per stage) ----
  const int ia = tid, ib = 256 + tid;
  const int ra = ia >> 3, ca = ia & 7, rb = ib >> 3, cb = ib & 7;
  const short* kpa = qkv + rowbase + Dd + h * Dh + (size_t)ra * N1 + (ca ^ (ra & 7)) * 8;
  const short* kpb = qkv + rowbase + Dd + h * Dh + (size_t)rb * N1 + (cb ^ (rb & 7)) * 8;
  const int Ta = ia >> 3, Tb = ib >> 3;
  const short* vpa = qkv + rowbase + 2 * Dd + h * Dh +
                     (size_t)((Ta & 15) * 4 + (ca >> 1)) * N1 + (Ta >> 4) * 16 + (ia & 1) * 8;
  const short* vpb = qkv + rowbase + 2 * Dd + h * Dh +
                     (size_t)((Tb & 15) * 4 + (cb >> 1)) * N1 + (Tb >> 4) * 16 + (ib & 1) * 8;
  char* KsB = (char*)&Ks[0][0];
  char* VtB = (char*)&Vt[0][0];
  const int dsta = ia * 16, dstb = ib * 16;

  // ---- hoisted LDS fragment offsets (bytes) ----
  int koff[4][2];
#pragma unroll
  for (int n = 0; n < 4; ++n) {
    koff[n][0] = ((n * 16 + li) * 64 + ((g ^ (li & 7)) & 7) * 8) * 2;
    koff[n][1] = ((n * 16 + li) * 64 + (((4 + g) ^ (li & 7)) & 7) * 8) * 2;
  }
  int pwoff[4], proff[2];
#pragma unroll
  for (int n = 0; n < 4; ++n)
    pwoff[n] = li * 128 + (((2 * n + (g >> 1)) ^ (li & 7)) << 4) + 8 * (g & 1);
#pragma unroll
  for (int kk = 0; kk < 2; ++kk)
    proff[kk] = li * 128 + (((4 * kk + g) ^ (li & 7)) << 4);
  char* Pw = (char*)&Ps[w][0];
  const unsigned vlane = (unsigned)((lane >> 4) * 256 + (lane & 15) * 2);
  const unsigned vbase0 = (unsigned)(unsigned long long)(&Vt[0][0]) + vlane;

  auto stage = [&](int buf) {
    const int bo = buf << 13;
    gload_lds16(kpa, KsB + bo + dsta);
    gload_lds16(kpb, KsB + bo + dstb);
    gload_lds16(vpa, VtB + bo + dsta);
    gload_lds16(vpb, VtB + bo + dstb);
    kpa += KVSTRIDE; kpb += KVSTRIDE; vpa += KVSTRIDE; vpb += KVSTRIDE;
  };

  stage(0);   // tile 0 -> buf 0
  stage(1);   // tile 1 -> buf 1   (8 loads in flight)

  for (int kt = 0; kt < NT; ++kt) {
    const int cur = kt & 1;
    const int curo = cur << 13;
    if (kt + 1 < NT) asm volatile("s_waitcnt vmcnt(4)" ::: "memory");
    else             asm volatile("s_waitcnt vmcnt(0)" ::: "memory");
    __builtin_amdgcn_s_barrier();
    __builtin_amdgcn_sched_barrier(0);

    // ---- Z^T = mfma(K, Q)  (raw dot products) ----
    f32x4 s[4];
    __builtin_amdgcn_s_setprio(1);
#pragma unroll
    for (int n = 0; n < 4; ++n) {
      s16x8 kf0 = *(const s16x8*)(KsB + curo + koff[n][0]);
      s16x8 kf1 = *(const s16x8*)(KsB + curo + koff[n][1]);
      f32x4 z;
#pragma unroll
      for (int r = 0; r < 4; ++r) z[r] = 0.f;
      z = mfma16(kf0, qf[0], z);
      z = mfma16(kf1, qf[1], z);
      s[n] = z;
    }
    __builtin_amdgcn_s_setprio(0);

    // ---- online softmax, raw-domain max, per-lane q = li ----
    const float l0 = fmaxf(fmaxf(s[0][0], s[0][1]), s[0][2]);
    const float l1 = fmaxf(fmaxf(s[0][3], s[1][0]), s[1][1]);
    const float l2 = fmaxf(fmaxf(s[1][2], s[1][3]), s[2][0]);
    const float l3 = fmaxf(fmaxf(s[2][1], s[2][2]), s[2][3]);
    const float l4 = fmaxf(fmaxf(s[3][0], s[3][1]), s[3][2]);
    float mx = fmaxf(fmaxf(fmaxf(fmaxf(l0, l1), l2), fmaxf(l3, l4)), s[3][3]);
    mx = redmax64(mx);
    if (!__all(mx - m_ <= kThrRaw)) {
      const float mnew = fmaxf(m_, mx);
      const float sc = fexp2((m_ - mnew) * kScale);
      float scq[4];
#pragma unroll
      for (int r = 0; r < 4; ++r)
        scq[r] = __shfl(sc, (lane & 48) + ((lane & 48) >> 2) + r, 64);
#pragma unroll
      for (int dn = 0; dn < 4; ++dn)
#pragma unroll
        for (int r = 0; r < 4; ++r) oa[dn][r] *= scq[r];
      l_ *= sc;
      m_ = mnew;
    }
    const float msc = m_ * kScale;
    float rs = 0.f;
#pragma unroll
    for (int n = 0; n < 4; ++n)
#pragma unroll
      for (int r = 0; r < 4; ++r) {
        const float p = fexp2(fmaf(s[n][r], kScale, -msc));
        s[n][r] = p;
        rs += p;
      }
    rs = redsum64(rs);
    l_ += rs;

    // ---- P pack via cvt_pk -> swizzled per-wave LDS (4 x ds_write_b64) ----
#pragma unroll
    for (int n = 0; n < 4; ++n) {
      unsigned u0, u1;
      asm("v_cvt_pk_bf16_f32 %0, %1, %2" : "=v"(u0) : "v"(s[n][0]), "v"(s[n][1]));
      asm("v_cvt_pk_bf16_f32 %0, %1, %2" : "=v"(u1) : "v"(s[n][2]), "v"(s[n][3]));
      i32x2 pv; pv[0] = (int)u0; pv[1] = (int)u1;
      *(i32x2*)(Pw + pwoff[n]) = pv;
    }

    // ---- P A-frag reads (2 x b128) ----
    s16x8 pf[2];
#pragma unroll
    for (int kk = 0; kk < 2; ++kk)
      pf[kk] = *(const s16x8*)(Pw + proff[kk]);

    // ---- V^T fragments via HW transpose reads (16 x ds_read_b64_tr_b16) ----
    union VU { long l[2]; s16x8 v; };
    VU vu[4][2];
    {
      const unsigned vaddr = vbase0 + (unsigned)curo;
      TRRD(vu[0][0].l[0], vaddr, 0);    TRRD(vu[0][0].l[1], vaddr, 128);
      TRRD(vu[0][1].l[0], vaddr, 1024); TRRD(vu[0][1].l[1], vaddr, 1152);
      TRRD(vu[1][0].l[0], vaddr, 2048); TRRD(vu[1][0].l[1], vaddr, 2176);
      TRRD(vu[1][1].l[0], vaddr, 3072); TRRD(vu[1][1].l[1], vaddr, 3200);
      TRRD(vu[2][0].l[0], vaddr, 4096); TRRD(vu[2][0].l[1], vaddr, 4224);
      TRRD(vu[2][1].l[0], vaddr, 5120); TRRD(vu[2][1].l[1], vaddr, 5248);
      TRRD(vu[3][0].l[0], vaddr, 6144); TRRD(vu[3][0].l[1], vaddr, 6272);
      TRRD(vu[3][1].l[0], vaddr, 7168); TRRD(vu[3][1].l[1], vaddr, 7296);
    }
    asm volatile("s_waitcnt lgkmcnt(0)" ::: "memory");
    __builtin_amdgcn_sched_barrier(0);

    // ---- O += P V ----
    __builtin_amdgcn_s_setprio(1);
#pragma unroll
    for (int dn = 0; dn < 4; ++dn) {
      oa[dn] = mfma16(pf[0], vu[dn][0].v, oa[dn]);
      oa[dn] = mfma16(pf[1], vu[dn][1].v, oa[dn]);
    }
    __builtin_amdgcn_s_setprio(0);

    __builtin_amdgcn_s_barrier();
    if (kt + 2 < NT) stage(cur);   // tile kt+2 -> buf cur
  }

  // ---- O / l -> bf16 obuf (row q = q0 + g*4 + r) ----
  {
#pragma unroll
    for (int r = 0; r < 4; ++r) {
      const float lq = __shfl(l_, (lane & 48) + ((lane & 48) >> 2) + r, 64);
      const float inv = frcp(lq);
      const int row = b * Ll + q0 + g * 4 + r;
#pragma unroll
      for (int dn = 0; dn < 4; ++dn)
        obuf[(size_t)row * Dd + h * Dh + dn * 16 + li] =
            (short)f2bf(oa[dn][r] * inv);
    }
  }
}

// ---------------------------------------------------------------------------
extern "C" void kernel_launch(void* const* d_in, const int* in_sizes, int n_in,
                              void* d_out, int out_size, void* d_ws, size_t ws_size,
                              hipStream_t stream) {
  const float* x     = (const float*)d_in[0];
  const float* gamma = (const float*)d_in[1];
  const float* beta  = (const float*)d_in[2];
  const float* w1    = (const float*)d_in[3];
  const float* b1    = (const float*)d_in[4];
  const float* w2    = (const float*)d_in[5];
  const float* b2    = (const float*)d_in[6];
  float* out = (float*)d_out;
  char* ws = (char*)d_ws;

  if (ws_size >= 29884416) {
    // ---- T1: full batch in one pass.  ws = 29,884,416 B ----
    short* qkvb = (short*)(ws);              // 4096*2304*2 = 18874368
    short* hb   = (short*)(ws + 18874368);   // 4096*768*2  = 6291456 (hbuf, then obuf)
    short* w1b  = (short*)(ws + 25165824);   // 2304*768*2  = 3538944
    short* w2b  = (short*)(ws + 28704768);   // 768*768*2   = 1179648
    prep_kernel<<<dim3(Mrows + 1024), dim3(256), 0, stream>>>(
        x, gamma, beta, hb, w1, w2, w1b, w2b);
    gemm_bt<0, 0><<<dim3(N1 / 128, Mrows / 128), dim3(256), 0, stream>>>(
        hb, w1b, b1, nullptr, (void*)qkvb, N1, Dd);
    attn_kernel<<<dim3(Ll / 64, Bb * Hh), dim3(256), 0, stream>>>(qkvb, hb);
    gemm_bt<1, 0><<<dim3(Dd / 128, Mrows / 128), dim3(256), 0, stream>>>(
        hb, w2b, b2, x, (void*)out, Dd, Dd);
  } else if (ws_size >= 17301504) {
    // ---- T2: per-batch, bf16 weights.  ws = 17,301,504 B ----
    short* qkvb = (short*)(ws);              // 2048*2304*2 = 9437184
    short* hb   = (short*)(ws + 9437184);    // 2048*768*2  = 3145728 (hbuf/obuf)
    short* w1b  = (short*)(ws + 12582912);   // 3538944
    short* w2b  = (short*)(ws + 16121856);   // 1179648
    cvt_kernel<<<dim3(1024), dim3(256), 0, stream>>>(w1, w2, w1b, w2b);
    for (int b = 0; b < Bb; ++b) {
      const size_t ro = (size_t)b * Ll * Dd;
      ln_kernel<<<dim3(Ll), dim3(256), 0, stream>>>(x + ro, gamma, beta, hb);
      gemm_bt<0, 0><<<dim3(N1 / 128, Ll / 128), dim3(256), 0, stream>>>(
          hb, w1b, b1, nullptr, (void*)qkvb, N1, Dd);
      attn_kernel<<<dim3(Ll / 64, Hh), dim3(256), 0, stream>>>(qkvb, hb);
      gemm_bt<1, 0><<<dim3(Dd / 128, Ll / 128), dim3(256), 0, stream>>>(
          hb, w2b, b2, x + ro, (void*)(out + ro), Dd, Dd);
    }
  } else {
    // ---- T3: per-batch, fp32 weights staged on the fly.  ws = 12,582,912 B ----
    short* qkvb = (short*)(ws);              // 9437184
    short* hb   = (short*)(ws + 9437184);    // 3145728 (hbuf/obuf)
    for (int b = 0; b < Bb; ++b) {
      const size_t ro = (size_t)b * Ll * Dd;
      ln_kernel<<<dim3(Ll), dim3(256), 0, stream>>>(x + ro, gamma, beta, hb);
      gemm_bt<0, 1><<<dim3(N1 / 128, Ll / 128), dim3(256), 0, stream>>>(
          hb, w1, b1, nullptr, (void*)qkvb, N1, Dd);
      attn_kernel<<<dim3(Ll / 64, Hh), dim3(256), 0, stream>>>(qkvb, hb);
      gemm_bt<1, 1><<<dim3(Dd / 128, Ll / 128), dim3(256), 0, stream>>>(
          hb, w2, b2, x + ro, (void*)(out + ro), Dd, Dd);
    }
  }
}

// Round 11
// 114.204 us; speedup vs baseline: 1.4392x; 1.0190x over previous
//
#include <hip/hip_runtime.h>

// ---------------------------------------------------------------------------
// Fused pre-LN MHA block on MI355X (gfx950).
// B=2, L=2048, D=768, H=12, Dh=64.  All matmuls via mfma_f32_16x16x32_bf16.
// Pipeline: prep(LN+cvt) -> GEMM1 (qkv) -> flash-attn -> GEMM2+residual
// R10: (a) attn zA/zB cross-tile pipeline — QK^T(t+1) issued before
// softmax(t) so MFMA overlaps the VALU/trans chain; staging split into
// stageK (top of iter) / stageV (end of iter) with vmcnt(2) counted waits.
// (b) XCD-aware chunked block swizzle on attn + both GEMMs (L2 locality;
// attn FETCH was 2.7x the qkv footprint).
// ---------------------------------------------------------------------------

#define DEV __device__ __forceinline__

typedef __attribute__((ext_vector_type(4))) float f32x4;
typedef __attribute__((ext_vector_type(8))) short s16x8;
typedef __attribute__((ext_vector_type(2))) int i32x2;

constexpr int Bb   = 2;
constexpr int Ll   = 2048;
constexpr int Dd   = 768;
constexpr int Hh   = 12;
constexpr int Dh   = 64;
constexpr int Mrows = Bb * Ll;      // 4096
constexpr int N1   = 3 * Dd;        // 2304

DEV unsigned short f2bf(float f) {
  union { float f; unsigned u; } v; v.f = f;
  unsigned r = v.u + 0x7fffu + ((v.u >> 16) & 1u);
  return (unsigned short)(r >> 16);
}

DEV void gload_lds16(const void* g, void* l) {
  __builtin_amdgcn_global_load_lds((const __attribute__((address_space(1))) unsigned int*)g,
                                   (__attribute__((address_space(3))) unsigned int*)l,
                                   16, 0, 0);
}

DEV f32x4 mfma16(s16x8 a, s16x8 b, f32x4 c) {
  return __builtin_amdgcn_mfma_f32_16x16x32_bf16(a, b, c, 0, 0, 0);
}

// single-instruction 2^x and 1/x (ocml paths are 10+ instrs without fast-math)
DEV float fexp2(float x) { float r; asm("v_exp_f32 %0, %1" : "=v"(r) : "v"(x)); return r; }
DEV float frcp(float x)  { float r; asm("v_rcp_f32 %0, %1" : "=v"(r) : "v"(x)); return r; }

// reduce over lanes {l, l^16, l^32, l^48}: shfl for xor16, permlane32 for xor32
DEV float redmax64(float x) {
  x = fmaxf(x, __shfl_xor(x, 16, 64));
  float a = x, b = x;
  asm volatile("v_permlane32_swap_b32 %0, %1" : "+v"(a), "+v"(b));
  return fmaxf(a, b);
}
DEV float redsum64(float x) {
  x += __shfl_xor(x, 16, 64);
  float a = x, b = x;
  asm volatile("v_permlane32_swap_b32 %0, %1" : "+v"(a), "+v"(b));
  return a + b;
}

// ---------------------------------------------------------------------------
// LN body (one block per row, 256 thr) — used by prep_kernel and ln_kernel.
// ---------------------------------------------------------------------------
DEV void ln_body(int row, int t, const float* __restrict__ x,
                 const float* __restrict__ gamma, const float* __restrict__ beta,
                 short* __restrict__ hbuf, float* red) {
  const float* xr = x + (size_t)row * Dd;
  float v0 = xr[t], v1 = xr[t + 256], v2 = xr[t + 512];
  float s = v0 + v1 + v2;
  float q = v0 * v0 + v1 * v1 + v2 * v2;
#pragma unroll
  for (int off = 32; off; off >>= 1) {
    s += __shfl_xor(s, off, 64);
    q += __shfl_xor(q, off, 64);
  }
  const int w = t >> 6, lane = t & 63;
  if (lane == 0) { red[w] = s; red[4 + w] = q; }
  __syncthreads();
  s = red[0] + red[1] + red[2] + red[3];
  q = red[4] + red[5] + red[6] + red[7];
  const float mean = s * (1.f / Dd);
  const float var  = q * (1.f / Dd) - mean * mean;
  const float rstd = rsqrtf(var + 1e-5f);
  short* hr = hbuf + (size_t)row * Dd;
  hr[t]       = (short)f2bf((v0 - mean) * rstd * gamma[t]       + beta[t]);
  hr[t + 256] = (short)f2bf((v1 - mean) * rstd * gamma[t + 256] + beta[t + 256]);
  hr[t + 512] = (short)f2bf((v2 - mean) * rstd * gamma[t + 512] + beta[t + 512]);
}

constexpr int W1E = N1 * Dd;     // 1769472
constexpr int W2E = Dd * Dd;     // 589824

__global__ __launch_bounds__(256) void ln_kernel(const float* __restrict__ x,
                                                 const float* __restrict__ gamma,
                                                 const float* __restrict__ beta,
                                                 short* __restrict__ hbuf) {
  __shared__ float red[8];
  ln_body(blockIdx.x, threadIdx.x, x, gamma, beta, hbuf, red);
}

__global__ __launch_bounds__(256) void cvt_kernel(const float* __restrict__ w1,
                                                  const float* __restrict__ w2,
                                                  short* __restrict__ w1b,
                                                  short* __restrict__ w2b) {
  int i = blockIdx.x * 256 + threadIdx.x;
  const int stride = gridDim.x * 256;
  for (; i < W1E + W2E; i += stride) {
    if (i < W1E) w1b[i] = (short)f2bf(w1[i]);
    else         w2b[i - W1E] = (short)f2bf(w2[i - W1E]);
  }
}

// fused LN (blocks 0..Mrows-1) + weight cvt (blocks Mrows..Mrows+1023)
__global__ __launch_bounds__(256) void prep_kernel(const float* __restrict__ x,
                                                   const float* __restrict__ gamma,
                                                   const float* __restrict__ beta,
                                                   short* __restrict__ hbuf,
                                                   const float* __restrict__ w1,
                                                   const float* __restrict__ w2,
                                                   short* __restrict__ w1b,
                                                   short* __restrict__ w2b) {
  __shared__ float red[8];
  if (blockIdx.x < (unsigned)Mrows) {
    ln_body(blockIdx.x, threadIdx.x, x, gamma, beta, hbuf, red);
  } else {
    int i = (blockIdx.x - Mrows) * 256 + threadIdx.x;
    for (; i < W1E + W2E; i += 1024 * 256) {
      if (i < W1E) w1b[i] = (short)f2bf(w1[i]);
      else         w2b[i - W1E] = (short)f2bf(w2[i - W1E]);
    }
  }
}

// XCD-aware chunked swizzle of the linear block id (bijective when nwg%8==0).
DEV unsigned xcd_swz(unsigned f, unsigned nwg) {
  if ((nwg & 7u) != 0u) return f;
  return (f & 7u) * (nwg >> 3) + (f >> 3);
}

// ---------------------------------------------------------------------------
// GEMM (B^T form): C[m][n] = sum_k A[m][k] * W[n][k] (+bias)(+resid)
// 128x128 tile, BK=64, 4 waves (2x2), each wave 64x64 = 4x4 16x16 frags.
// WSRC 0: double-buffered LDS + counted-vmcnt pipeline (raw barriers).
// WSRC 1 (fp32 weights, T3 tier): old single-buffer __syncthreads loop.
// LDS tiles XOR-swizzled via pre-swizzled global source (m173 pattern).
// Block coords XCD-swizzled for L2 locality.
// ---------------------------------------------------------------------------
template <int EPI, int WSRC>
__global__ __launch_bounds__(256) void gemm_bt(const short* __restrict__ A,
                                               const void* __restrict__ Wp,
                                               const float* __restrict__ bias,
                                               const float* __restrict__ resid,
                                               void* __restrict__ outp,
                                               int N, int K) {
  __shared__ __align__(16) short As[2][128 * 64];
  __shared__ __align__(16) short Ws[2][128 * 64];
  const int tid  = threadIdx.x;
  const int lane = tid & 63, wid = tid >> 6;
  const int wr = wid >> 1, wc = wid & 1;
  const int g = lane >> 4, li = lane & 15;
  const unsigned o = xcd_swz(blockIdx.y * gridDim.x + blockIdx.x,
                             gridDim.x * gridDim.y);
  const int brow = (int)(o / gridDim.x) * 128, bcol = (int)(o % gridDim.x) * 128;

  f32x4 acc[4][4];
#pragma unroll
  for (int m = 0; m < 4; ++m)
#pragma unroll
    for (int n = 0; n < 4; ++n)
#pragma unroll
      for (int r = 0; r < 4; ++r) acc[m][n][r] = 0.f;

  if constexpr (WSRC == 0) {
    const short* W = (const short*)Wp;
    const int nt = K >> 6;
    auto stage = [&](int t, int buf) {
      const int ko = t << 6;
#pragma unroll
      for (int i = 0; i < 4; ++i) {
        const int idx = i * 256 + tid;
        const int r = idx >> 3, c = idx & 7;
        const int cs = c ^ (r & 7);
        gload_lds16(A + (size_t)(brow + r) * K + ko + cs * 8,
                    (char*)&As[buf][0] + idx * 16);
        gload_lds16(W + (size_t)(bcol + r) * K + ko + cs * 8,
                    (char*)&Ws[buf][0] + idx * 16);
      }
    };
    stage(0, 0);
    stage(1, 1);
    for (int it = 0; it < nt; ++it) {
      const int cur = it & 1;
      if (it + 1 < nt) asm volatile("s_waitcnt vmcnt(8)" ::: "memory");
      else             asm volatile("s_waitcnt vmcnt(0)" ::: "memory");
      __builtin_amdgcn_s_barrier();
      __builtin_amdgcn_sched_barrier(0);
#pragma unroll
      for (int kk = 0; kk < 2; ++kk) {
        s16x8 af[4], bf[4];
#pragma unroll
        for (int m = 0; m < 4; ++m) {
          const int row = wr * 64 + m * 16 + li;
          af[m] = *(const s16x8*)&As[cur][row * 64 + (((kk * 4 + g) ^ (li & 7)) & 7) * 8];
        }
#pragma unroll
        for (int n = 0; n < 4; ++n) {
          const int row = wc * 64 + n * 16 + li;
          bf[n] = *(const s16x8*)&Ws[cur][row * 64 + (((kk * 4 + g) ^ (li & 7)) & 7) * 8];
        }
#pragma unroll
        for (int m = 0; m < 4; ++m)
#pragma unroll
          for (int n = 0; n < 4; ++n)
            acc[m][n] = mfma16(af[m], bf[n], acc[m][n]);
      }
      __builtin_amdgcn_s_barrier();
      if (it + 2 < nt) stage(it + 2, cur);
    }
  } else {
    const float* W = (const float*)Wp;
    for (int kt = 0; kt < K; kt += 64) {
#pragma unroll
      for (int i = 0; i < 4; ++i) {
        const int idx = i * 256 + tid;
        const int r = idx >> 3, c = idx & 7;
        const int cs = c ^ (r & 7);
        gload_lds16(A + (size_t)(brow + r) * K + kt + cs * 8,
                    (char*)&As[0][0] + idx * 16);
      }
#pragma unroll
      for (int i = 0; i < 4; ++i) {
        const int idx = i * 256 + tid;
        const int r = idx >> 3, c = idx & 7;
        const float* wp = W + (size_t)(bcol + r) * K + kt + c * 8;
        const f32x4 lo = *(const f32x4*)wp;
        const f32x4 hi = *(const f32x4*)(wp + 4);
        s16x8 oo;
#pragma unroll
        for (int j = 0; j < 4; ++j) {
          oo[j]     = (short)f2bf(lo[j]);
          oo[4 + j] = (short)f2bf(hi[j]);
        }
        *(s16x8*)((char*)&Ws[0][0] + (size_t)(r * 8 + (c ^ (r & 7))) * 16) = oo;
      }
      __syncthreads();
#pragma unroll
      for (int kk = 0; kk < 2; ++kk) {
        s16x8 af[4], bf[4];
#pragma unroll
        for (int m = 0; m < 4; ++m) {
          const int row = wr * 64 + m * 16 + li;
          af[m] = *(const s16x8*)&As[0][row * 64 + (((kk * 4 + g) ^ (li & 7)) & 7) * 8];
        }
#pragma unroll
        for (int n = 0; n < 4; ++n) {
          const int row = wc * 64 + n * 16 + li;
          bf[n] = *(const s16x8*)&Ws[0][row * 64 + (((kk * 4 + g) ^ (li & 7)) & 7) * 8];
        }
#pragma unroll
        for (int m = 0; m < 4; ++m)
#pragma unroll
          for (int n = 0; n < 4; ++n)
            acc[m][n] = mfma16(af[m], bf[n], acc[m][n]);
      }
      __syncthreads();
    }
  }

#pragma unroll
  for (int m = 0; m < 4; ++m) {
#pragma unroll
    for (int n = 0; n < 4; ++n) {
      const int col = bcol + wc * 64 + n * 16 + li;
      const float bv = bias[col];
#pragma unroll
      for (int r = 0; r < 4; ++r) {
        const int row = brow + wr * 64 + m * 16 + g * 4 + r;
        const float v = acc[m][n][r] + bv;
        if (EPI == 0) {
          ((short*)outp)[(size_t)row * N + col] = (short)f2bf(v);
        } else {
          const size_t o2 = (size_t)row * N + col;
          ((float*)outp)[o2] = v + resid[o2];
        }
      }
    }
  }
}

// ---------------------------------------------------------------------------
// Flash attention R10 (= R9 + zA/zB cross-tile pipeline + XCD swizzle).
// Grid (32, nb*12), 256 thr = 4 waves; wave owns 16 q rows.  KVBLK=64.
// Staging split: stageK(t+2) at TOP of iter t (K[cur] dead there),
// stageV(t+2) at END.  vmcnt audit (2 loads per stage call, in issue order):
//   top of iter t outstanding: V(t+1)[end t-1], K(t+2)[top t-1? no: top t]..
//   actually: V(t+1), then this iter issues K(t+2) after the wait.
//   vmcnt(2) at top of iter t leaves <=2 outstanding -> everything up to and
//   including K(t+1) [top of t-1] and V(t) [end of t-2] complete; V(t+1) may
//   remain in flight.  zB=QK(t+1) reads K[cur^1] (ready), PV reads V[cur]
//   (ready).  Barrier after wait makes other waves' loads visible.
// ---------------------------------------------------------------------------
#define TRRD(dst, addr, OFF)                                                   \
  asm volatile("ds_read_b64_tr_b16 %0, %1 offset:" #OFF                        \
               : "=v"(dst) : "v"(addr))

__global__ __launch_bounds__(256) void attn_kernel(const short* __restrict__ qkv,
                                                   short* __restrict__ obuf) {
  __shared__ __align__(16) short Ks[2][64 * 64];
  __shared__ __align__(16) short Vt[2][64 * 64];
  __shared__ __align__(16) short Ps[4][16 * 64];
  const int tid  = threadIdx.x;
  const int lane = tid & 63, w = tid >> 6;
  const int g = lane >> 4, li = lane & 15;
  // XCD swizzle: consecutive swizzled-x blocks (same (b,h) K/V panel) land on
  // the same XCD -> panel stays in that XCD's L2.
  const unsigned o = xcd_swz(blockIdx.y * 32u + blockIdx.x, gridDim.x * gridDim.y);
  const int bh = (int)(o >> 5);
  const int b = bh / Hh, h = bh % Hh;
  const size_t rowbase = (size_t)b * Ll * N1;
  const int q0 = (int)(o & 31u) * 64 + w * 16;
  constexpr float kScale = 0.125f * 1.44269504f;   // 1/sqrt(Dh) * log2(e)
  constexpr float kThrRaw = 8.f / kScale;          // defer-max threshold (raw)
  constexpr int KVSTRIDE = 64 * N1;                // elements per KV tile

  // Q fragments (B operand of swapped QK^T)
  s16x8 qf[2];
#pragma unroll
  for (int ks = 0; ks < 2; ++ks)
    qf[ks] = *(const s16x8*)(qkv + rowbase + (size_t)(q0 + li) * N1 +
                             h * Dh + ks * 32 + g * 8);

  f32x4 oa[4];
  float m_ = -1e30f, l_ = 0.f;   // per-lane: q = li ; m_ in RAW domain
#pragma unroll
  for (int dn = 0; dn < 4; ++dn)
#pragma unroll
    for (int r = 0; r < 4; ++r) oa[dn][r] = 0.f;

  constexpr int NT = Ll / 64;  // 32 tiles

  // ---- hoisted staging source pointers (advance per stage call) ----
  const int ia = tid, ib = 256 + tid;
  const int ra = ia >> 3, ca = ia & 7, rb = ib >> 3, cb = ib & 7;
  const short* kpa = qkv + rowbase + Dd + h * Dh + (size_t)ra * N1 + (ca ^ (ra & 7)) * 8;
  const short* kpb = qkv + rowbase + Dd + h * Dh + (size_t)rb * N1 + (cb ^ (rb & 7)) * 8;
  const int Ta = ia >> 3, Tb = ib >> 3;
  const short* vpa = qkv + rowbase + 2 * Dd + h * Dh +
                     (size_t)((Ta & 15) * 4 + (ca >> 1)) * N1 + (Ta >> 4) * 16 + (ia & 1) * 8;
  const short* vpb = qkv + rowbase + 2 * Dd + h * Dh +
                     (size_t)((Tb & 15) * 4 + (cb >> 1)) * N1 + (Tb >> 4) * 16 + (ib & 1) * 8;
  char* KsB = (char*)&Ks[0][0];
  char* VtB = (char*)&Vt[0][0];
  const int dsta = ia * 16, dstb = ib * 16;

  // ---- hoisted LDS fragment offsets (bytes) ----
  int koff[4][2];
#pragma unroll
  for (int n = 0; n < 4; ++n) {
    koff[n][0] = ((n * 16 + li) * 64 + ((g ^ (li & 7)) & 7) * 8) * 2;
    koff[n][1] = ((n * 16 + li) * 64 + (((4 + g) ^ (li & 7)) & 7) * 8) * 2;
  }
  int pwoff[4], proff[2];
#pragma unroll
  for (int n = 0; n < 4; ++n)
    pwoff[n] = li * 128 + (((2 * n + (g >> 1)) ^ (li & 7)) << 4) + 8 * (g & 1);
#pragma unroll
  for (int kk = 0; kk < 2; ++kk)
    proff[kk] = li * 128 + (((4 * kk + g) ^ (li & 7)) << 4);
  char* Pw = (char*)&Ps[w][0];
  const unsigned vlane = (unsigned)((lane >> 4) * 256 + (lane & 15) * 2);
  const unsigned vbase0 = (unsigned)(unsigned long long)(&Vt[0][0]) + vlane;

  auto stageK = [&](int buf) {
    const int bo = buf << 13;
    gload_lds16(kpa, KsB + bo + dsta);
    gload_lds16(kpb, KsB + bo + dstb);
    kpa += KVSTRIDE; kpb += KVSTRIDE;
  };
  auto stageV = [&](int buf) {
    const int bo = buf << 13;
    gload_lds16(vpa, VtB + bo + dsta);
    gload_lds16(vpb, VtB + bo + dstb);
    vpa += KVSTRIDE; vpb += KVSTRIDE;
  };

  // prologue: K0 V0 K1 V1 (8 loads); wait K0+V0, leave K1+V1 in flight
  stageK(0); stageV(0); stageK(1); stageV(1);
  asm volatile("s_waitcnt vmcnt(4)" ::: "memory");
  __builtin_amdgcn_s_barrier();
  __builtin_amdgcn_sched_barrier(0);

  // zA = QK^T(tile 0)
  f32x4 zA[4], zB[4];
#pragma unroll
  for (int n = 0; n < 4; ++n) {
    s16x8 kf0 = *(const s16x8*)(KsB + koff[n][0]);
    s16x8 kf1 = *(const s16x8*)(KsB + koff[n][1]);
    f32x4 z;
#pragma unroll
    for (int r = 0; r < 4; ++r) z[r] = 0.f;
    z = mfma16(kf0, qf[0], z);
    z = mfma16(kf1, qf[1], z);
    zA[n] = z;
  }

  for (int kt = 0; kt < NT; ++kt) {
    const int cur = kt & 1;
    const int curo = cur << 13;
    const int nxto = (cur ^ 1) << 13;
    if (kt + 1 < NT) asm volatile("s_waitcnt vmcnt(2)" ::: "memory");
    else             asm volatile("s_waitcnt vmcnt(0)" ::: "memory");
    __builtin_amdgcn_s_barrier();
    __builtin_amdgcn_sched_barrier(0);

    // K[cur] is dead (zA computed last iter) -> refill it now
    if (kt + 2 < NT) stageK(cur);

    // ---- zB = QK^T(tile kt+1) — independent MFMAs overlapping softmax ----
    if (kt + 1 < NT) {
      __builtin_amdgcn_s_setprio(1);
#pragma unroll
      for (int n = 0; n < 4; ++n) {
        s16x8 kf0 = *(const s16x8*)(KsB + nxto + koff[n][0]);
        s16x8 kf1 = *(const s16x8*)(KsB + nxto + koff[n][1]);
        f32x4 z;
#pragma unroll
        for (int r = 0; r < 4; ++r) z[r] = 0.f;
        z = mfma16(kf0, qf[0], z);
        z = mfma16(kf1, qf[1], z);
        zB[n] = z;
      }
      __builtin_amdgcn_s_setprio(0);
    }

    // ---- online softmax on zA, raw-domain max, per-lane q = li ----
    const float l0 = fmaxf(fmaxf(zA[0][0], zA[0][1]), zA[0][2]);
    const float l1 = fmaxf(fmaxf(zA[0][3], zA[1][0]), zA[1][1]);
    const float l2 = fmaxf(fmaxf(zA[1][2], zA[1][3]), zA[2][0]);
    const float l3 = fmaxf(fmaxf(zA[2][1], zA[2][2]), zA[2][3]);
    const float l4 = fmaxf(fmaxf(zA[3][0], zA[3][1]), zA[3][2]);
    float mx = fmaxf(fmaxf(fmaxf(fmaxf(l0, l1), l2), fmaxf(l3, l4)), zA[3][3]);
    mx = redmax64(mx);
    if (!__all(mx - m_ <= kThrRaw)) {
      const float mnew = fmaxf(m_, mx);
      const float sc = fexp2((m_ - mnew) * kScale);
      float scq[4];
#pragma unroll
      for (int r = 0; r < 4; ++r)
        scq[r] = __shfl(sc, (lane & 48) + ((lane & 48) >> 2) + r, 64);
#pragma unroll
      for (int dn = 0; dn < 4; ++dn)
#pragma unroll
        for (int r = 0; r < 4; ++r) oa[dn][r] *= scq[r];
      l_ *= sc;
      m_ = mnew;
    }
    const float msc = m_ * kScale;
    float rs = 0.f;
#pragma unroll
    for (int n = 0; n < 4; ++n)
#pragma unroll
      for (int r = 0; r < 4; ++r) {
        const float p = fexp2(fmaf(zA[n][r], kScale, -msc));
        zA[n][r] = p;
        rs += p;
      }
    rs = redsum64(rs);
    l_ += rs;

    // ---- P pack via cvt_pk -> swizzled per-wave LDS (4 x ds_write_b64) ----
#pragma unroll
    for (int n = 0; n < 4; ++n) {
      unsigned u0, u1;
      asm("v_cvt_pk_bf16_f32 %0, %1, %2" : "=v"(u0) : "v"(zA[n][0]), "v"(zA[n][1]));
      asm("v_cvt_pk_bf16_f32 %0, %1, %2" : "=v"(u1) : "v"(zA[n][2]), "v"(zA[n][3]));
      i32x2 pv; pv[0] = (int)u0; pv[1] = (int)u1;
      *(i32x2*)(Pw + pwoff[n]) = pv;
    }

    // ---- P A-frag reads (2 x b128) ----
    s16x8 pf[2];
#pragma unroll
    for (int kk = 0; kk < 2; ++kk)
      pf[kk] = *(const s16x8*)(Pw + proff[kk]);

    // ---- V^T fragments via HW transpose reads (16 x ds_read_b64_tr_b16) ----
    union VU { long l[2]; s16x8 v; };
    VU vu[4][2];
    {
      const unsigned vaddr = vbase0 + (unsigned)curo;
      TRRD(vu[0][0].l[0], vaddr, 0);    TRRD(vu[0][0].l[1], vaddr, 128);
      TRRD(vu[0][1].l[0], vaddr, 1024); TRRD(vu[0][1].l[1], vaddr, 1152);
      TRRD(vu[1][0].l[0], vaddr, 2048); TRRD(vu[1][0].l[1], vaddr, 2176);
      TRRD(vu[1][1].l[0], vaddr, 3072); TRRD(vu[1][1].l[1], vaddr, 3200);
      TRRD(vu[2][0].l[0], vaddr, 4096); TRRD(vu[2][0].l[1], vaddr, 4224);
      TRRD(vu[2][1].l[0], vaddr, 5120); TRRD(vu[2][1].l[1], vaddr, 5248);
      TRRD(vu[3][0].l[0], vaddr, 6144); TRRD(vu[3][0].l[1], vaddr, 6272);
      TRRD(vu[3][1].l[0], vaddr, 7168); TRRD(vu[3][1].l[1], vaddr, 7296);
    }
    asm volatile("s_waitcnt lgkmcnt(0)" ::: "memory");
    __builtin_amdgcn_sched_barrier(0);

    // ---- O += P V ----
    __builtin_amdgcn_s_setprio(1);
#pragma unroll
    for (int dn = 0; dn < 4; ++dn) {
      oa[dn] = mfma16(pf[0], vu[dn][0].v, oa[dn]);
      oa[dn] = mfma16(pf[1], vu[dn][1].v, oa[dn]);
    }
    __builtin_amdgcn_s_setprio(0);

    __builtin_amdgcn_s_barrier();   // all waves done reading V[cur] / Ps
    if (kt + 2 < NT) stageV(cur);   // refill V[cur] with tile kt+2
    if (kt + 1 < NT) {
#pragma unroll
      for (int n = 0; n < 4; ++n) zA[n] = zB[n];
    }
  }

  // ---- O / l -> bf16 obuf (row q = q0 + g*4 + r) ----
  {
#pragma unroll
    for (int r = 0; r < 4; ++r) {
      const float lq = __shfl(l_, (lane & 48) + ((lane & 48) >> 2) + r, 64);
      const float inv = frcp(lq);
      const int row = b * Ll + q0 + g * 4 + r;
#pragma unroll
      for (int dn = 0; dn < 4; ++dn)
        obuf[(size_t)row * Dd + h * Dh + dn * 16 + li] =
            (short)f2bf(oa[dn][r] * inv);
    }
  }
}

// ---------------------------------------------------------------------------
extern "C" void kernel_launch(void* const* d_in, const int* in_sizes, int n_in,
                              void* d_out, int out_size, void* d_ws, size_t ws_size,
                              hipStream_t stream) {
  const float* x     = (const float*)d_in[0];
  const float* gamma = (const float*)d_in[1];
  const float* beta  = (const float*)d_in[2];
  const float* w1    = (const float*)d_in[3];
  const float* b1    = (const float*)d_in[4];
  const float* w2    = (const float*)d_in[5];
  const float* b2    = (const float*)d_in[6];
  float* out = (float*)d_out;
  char* ws = (char*)d_ws;

  if (ws_size >= 29884416) {
    // ---- T1: full batch in one pass.  ws = 29,884,416 B ----
    short* qkvb = (short*)(ws);              // 4096*2304*2 = 18874368
    short* hb   = (short*)(ws + 18874368);   // 4096*768*2  = 6291456 (hbuf, then obuf)
    short* w1b  = (short*)(ws + 25165824);   // 2304*768*2  = 3538944
    short* w2b  = (short*)(ws + 28704768);   // 768*768*2   = 1179648
    prep_kernel<<<dim3(Mrows + 1024), dim3(256), 0, stream>>>(
        x, gamma, beta, hb, w1, w2, w1b, w2b);
    gemm_bt<0, 0><<<dim3(N1 / 128, Mrows / 128), dim3(256), 0, stream>>>(
        hb, w1b, b1, nullptr, (void*)qkvb, N1, Dd);
    attn_kernel<<<dim3(Ll / 64, Bb * Hh), dim3(256), 0, stream>>>(qkvb, hb);
    gemm_bt<1, 0><<<dim3(Dd / 128, Mrows / 128), dim3(256), 0, stream>>>(
        hb, w2b, b2, x, (void*)out, Dd, Dd);
  } else if (ws_size >= 17301504) {
    // ---- T2: per-batch, bf16 weights.  ws = 17,301,504 B ----
    short* qkvb = (short*)(ws);              // 2048*2304*2 = 9437184
    short* hb   = (short*)(ws + 9437184);    // 2048*768*2  = 3145728 (hbuf/obuf)
    short* w1b  = (short*)(ws + 12582912);   // 3538944
    short* w2b  = (short*)(ws + 16121856);   // 1179648
    cvt_kernel<<<dim3(1024), dim3(256), 0, stream>>>(w1, w2, w1b, w2b);
    for (int b = 0; b < Bb; ++b) {
      const size_t ro = (size_t)b * Ll * Dd;
      ln_kernel<<<dim3(Ll), dim3(256), 0, stream>>>(x + ro, gamma, beta, hb);
      gemm_bt<0, 0><<<dim3(N1 / 128, Ll / 128), dim3(256), 0, stream>>>(
          hb, w1b, b1, nullptr, (void*)qkvb, N1, Dd);
      attn_kernel<<<dim3(Ll / 64, Hh), dim3(256), 0, stream>>>(qkvb, hb);
      gemm_bt<1, 0><<<dim3(Dd / 128, Ll / 128), dim3(256), 0, stream>>>(
          hb, w2b, b2, x + ro, (void*)(out + ro), Dd, Dd);
    }
  } else {
    // ---- T3: per-batch, fp32 weights staged on the fly.  ws = 12,582,912 B ----
    short* qkvb = (short*)(ws);              // 9437184
    short* hb   = (short*)(ws + 9437184);    // 3145728 (hbuf/obuf)
    for (int b = 0; b < Bb; ++b) {
      const size_t ro = (size_t)b * Ll * Dd;
      ln_kernel<<<dim3(Ll), dim3(256), 0, stream>>>(x + ro, gamma, beta, hb);
      gemm_bt<0, 1><<<dim3(N1 / 128, Ll / 128), dim3(256), 0, stream>>>(
          hb, w1, b1, nullptr, (void*)qkvb, N1, Dd);
      attn_kernel<<<dim3(Ll / 64, Hh), dim3(256), 0, stream>>>(qkvb, hb);
      gemm_bt<1, 1><<<dim3(Dd / 128, Ll / 128), dim3(256), 0, stream>>>(
          hb, w2, b2, x + ro, (void*)(out + ro), Dd, Dd);
    }
  }
}